// Round 4
// baseline (985.709 us; speedup 1.0000x reference)
//
#include <hip/hip_runtime.h>
#include <stdint.h>

#define NN 20000
#define NE 200000   // must be a multiple of 16 (it is: 12500 waves)
// H=128, NH=8, HD=16, RBF=64

typedef __attribute__((ext_vector_type(8))) short bf16x8;
typedef __attribute__((ext_vector_type(4))) float f32x4;

__device__ __forceinline__ float bf2f(uint32_t u) {
  union { uint32_t i; float f; } v; v.i = u << 16; return v.f;
}
__device__ __forceinline__ uint16_t f2bf(float f) {
  union { float f; uint32_t i; } v; v.f = f;
  return (uint16_t)((v.i + 0x7fffu + ((v.i >> 16) & 1u)) >> 16);
}
__device__ __forceinline__ uint32_t pk2(float lo, float hi) {
  return (uint32_t)f2bf(lo) | ((uint32_t)f2bf(hi) << 16);
}
__device__ __forceinline__ float siluf(float x) { return x / (1.f + __expf(-x)); }

// ---------------- prep kernels ----------------

// dst[c*K + k] = bf16(src[k*C + c])   (dst is [C rows][K cols])
__global__ void k_transpose_cast(const float* __restrict__ src, uint16_t* __restrict__ dst,
                                 int K, int C) {
  int idx = blockIdx.x * 256 + threadIdx.x;
  if (idx >= K * C) return;
  int c = idx / K, k = idx - c * K;
  dst[idx] = f2bf(src[(size_t)k * C + c]);
}

__global__ void k_bias_concat(const float* __restrict__ bq, const float* __restrict__ bk,
                              const float* __restrict__ bv, const float* __restrict__ bdk,
                              const float* __restrict__ bdv, float* __restrict__ Bqkv,
                              float* __restrict__ Bdkv) {
  int t = blockIdx.x * 256 + threadIdx.x;
  if (t < 640) Bqkv[t] = (t < 128) ? bq[t] : ((t < 256) ? bk[t - 128] : bv[t - 256]);
  if (t < 512) Bdkv[t] = (t < 128) ? bdk[t] : bdv[t - 128];
}

// LayerNorm over H=128 per node, one wave per node, output bf16
__global__ void k_ln_cast(const float* __restrict__ x, const float* __restrict__ s,
                          const float* __restrict__ b, uint16_t* __restrict__ out) {
  int gt = blockIdx.x * 256 + threadIdx.x;
  int node = gt >> 6, lane = gt & 63;
  if (node >= NN) return;
  const float* row = x + (size_t)node * 128;
  float2 v = *(const float2*)&row[lane * 2];
  float sum = v.x + v.y, sq = v.x * v.x + v.y * v.y;
  #pragma unroll
  for (int off = 32; off; off >>= 1) { sum += __shfl_xor(sum, off); sq += __shfl_xor(sq, off); }
  float mu = sum * (1.f / 128.f);
  float var = sq * (1.f / 128.f) - mu * mu;
  float rs = rsqrtf(var + 1e-6f);
  float o0 = (v.x - mu) * rs * s[lane * 2] + b[lane * 2];
  float o1 = (v.y - mu) * rs * s[lane * 2 + 1] + b[lane * 2 + 1];
  ((uint32_t*)out)[(size_t)node * 64 + lane] = pk2(o0, o1);
}

__global__ void k_cast_bf16(const float* __restrict__ src, uint16_t* __restrict__ dst, int npairs) {
  int i = blockIdx.x * 256 + threadIdx.x;
  if (i >= npairs) return;
  float2 v = ((const float2*)src)[i];
  ((uint32_t*)dst)[i] = pk2(v.x, v.y);
}

// ---------------- edge sort by receiver (counting sort, parallel scan) ----------------
__global__ void k_hist(const int* __restrict__ rcv, int* __restrict__ deg) {
  int e = blockIdx.x * 256 + threadIdx.x;
  if (e < NE) atomicAdd(&deg[rcv[e]], 1);
}

__global__ void k_scan1(const int* __restrict__ deg, int* __restrict__ bsum) {
  __shared__ int ws[4];
  int i = blockIdx.x * 256 + threadIdx.x;
  int x = (i < NN) ? deg[i] : 0;
  #pragma unroll
  for (int d = 32; d; d >>= 1) x += __shfl_xor(x, d);
  if ((threadIdx.x & 63) == 0) ws[threadIdx.x >> 6] = x;
  __syncthreads();
  if (threadIdx.x == 0) bsum[blockIdx.x] = ws[0] + ws[1] + ws[2] + ws[3];
}

__global__ void k_scan2(int* __restrict__ bsum, int nb, int* __restrict__ off) {
  int lane = threadIdx.x;
  int carry = 0;
  for (int base = 0; base < nb; base += 64) {
    int i = base + lane;
    int x = (i < nb) ? bsum[i] : 0;
    int v = x;
    #pragma unroll
    for (int d = 1; d < 64; d <<= 1) { int y = __shfl_up(v, d); if (lane >= d) v += y; }
    if (i < nb) bsum[i] = carry + v - x;
    carry += __shfl(v, 63);
  }
  if (lane == 0) off[NN] = carry;   // == NE
}

__global__ void k_scan3(const int* __restrict__ deg, const int* __restrict__ bsum,
                        int* __restrict__ off, int* __restrict__ cur) {
  __shared__ int ws[4];
  int t = threadIdx.x, lane = t & 63, w = t >> 6;
  int i = blockIdx.x * 256 + t;
  int x = (i < NN) ? deg[i] : 0;
  int v = x;
  #pragma unroll
  for (int d = 1; d < 64; d <<= 1) { int y = __shfl_up(v, d); if (lane >= d) v += y; }
  if (lane == 63) ws[w] = v;
  __syncthreads();
  int wadd = 0;
  for (int j = 0; j < w; j++) wadd += ws[j];
  int excl = bsum[blockIdx.x] + wadd + v - x;
  if (i < NN) { off[i] = excl; cur[i] = excl; }
}

__global__ void k_scatter(const int* __restrict__ rcv, int* __restrict__ cur,
                          int* __restrict__ perm) {
  int e = blockIdx.x * 256 + threadIdx.x;
  if (e >= NE) return;
  int pos = atomicAdd(&cur[rcv[e]], 1);
  perm[pos] = e;
}

// permute per-edge scalars into sorted order
__global__ void k_permute(const int* __restrict__ perm, const int* __restrict__ snd,
                          const int* __restrict__ rcv, const float* __restrict__ ew,
                          const float* __restrict__ evec, int* __restrict__ sndp,
                          int* __restrict__ rcvp, float4* __restrict__ edata) {
  int i = blockIdx.x * 256 + threadIdx.x;
  if (i >= NE) return;
  int e = perm[i];
  sndp[i] = snd[e];
  rcvp[i] = rcv[e];
  edata[i] = make_float4(evec[e * 3], evec[e * 3 + 1], evec[e * 3 + 2], ew[e]);
}

// ---------------- bf16 MFMA GEMM: C = act(A @ BT^T + bias) ----------------
template <int KTOT, bool OUT_BF16, bool SILU>
__global__ __launch_bounds__(256) void k_gemm(const uint16_t* __restrict__ A,
                                              const uint16_t* __restrict__ BT,
                                              const float* __restrict__ bias,
                                              void* __restrict__ Cout, int M, int Fo) {
  __shared__ __align__(16) uint16_t As[128 * 72];
  __shared__ __align__(16) uint16_t Bs[128 * 72];
  int t = threadIdx.x;
  int l = t & 63;
  int row0 = blockIdx.y * 128, col0 = blockIdx.x * 128;
  int wm = ((t >> 6) >> 1) * 64, wn = ((t >> 6) & 1) * 64;
  f32x4 acc[4][4] = {};
  for (int kt = 0; kt < KTOT; kt += 64) {
    __syncthreads();
    #pragma unroll
    for (int i = 0; i < 4; i++) {
      int c = i * 256 + t;
      int row = c >> 3, ko = (c & 7) * 8;
      uint4 av = make_uint4(0u, 0u, 0u, 0u);
      int gr = row0 + row;
      if (gr < M) av = *(const uint4*)&A[(size_t)gr * KTOT + kt + ko];
      *(uint4*)&As[row * 72 + ko] = av;
      uint4 bw = *(const uint4*)&BT[(size_t)(col0 + row) * KTOT + kt + ko];
      *(uint4*)&Bs[row * 72 + ko] = bw;
    }
    __syncthreads();
    #pragma unroll
    for (int kk = 0; kk < 64; kk += 32) {
      bf16x8 af[4], bfr[4];
      #pragma unroll
      for (int mf = 0; mf < 4; mf++)
        af[mf] = *(const bf16x8*)&As[(wm + mf * 16 + (l & 15)) * 72 + (l >> 4) * 8 + kk];
      #pragma unroll
      for (int nf = 0; nf < 4; nf++)
        bfr[nf] = *(const bf16x8*)&Bs[(wn + nf * 16 + (l & 15)) * 72 + (l >> 4) * 8 + kk];
      #pragma unroll
      for (int mf = 0; mf < 4; mf++)
        #pragma unroll
        for (int nf = 0; nf < 4; nf++)
          acc[mf][nf] = __builtin_amdgcn_mfma_f32_16x16x32_bf16(af[mf], bfr[nf], acc[mf][nf], 0, 0, 0);
    }
  }
  float* Cf = (float*)Cout;
  uint16_t* Cb = (uint16_t*)Cout;
  #pragma unroll
  for (int mf = 0; mf < 4; mf++) {
    #pragma unroll
    for (int r = 0; r < 4; r++) {
      int grow = row0 + wm + mf * 16 + (l >> 4) * 4 + r;
      if (grow >= M) continue;
      #pragma unroll
      for (int nf = 0; nf < 4; nf++) {
        int gcol = col0 + wn + nf * 16 + (l & 15);
        float v = acc[mf][nf][r];
        if (bias) v += bias[gcol];
        if (SILU) v = siluf(v);
        if (OUT_BF16) Cb[(size_t)grow * Fo + gcol] = f2bf(v);
        else          Cf[(size_t)grow * Fo + gcol] = v;
      }
    }
  }
}

// ---------------- per-head LN on q/k (bf16 in/out) ----------------
__global__ void k_headln(const uint16_t* __restrict__ qkv, const float* __restrict__ qs,
                         const float* __restrict__ qb, const float* __restrict__ ks,
                         const float* __restrict__ kb, uint16_t* __restrict__ out) {
  int idx = blockIdx.x * 256 + threadIdx.x;
  if (idx >= NN * 16) return;
  int n = idx >> 4, ph = idx & 15, part = ph >> 3, h = ph & 7;
  const uint16_t* src = qkv + (size_t)n * 640 + part * 128 + h * 16;
  float v[16], sum = 0.f;
  #pragma unroll
  for (int i = 0; i < 16; i++) { v[i] = bf2f(src[i]); sum += v[i]; }
  float mu = sum * (1.f / 16.f), var = 0.f;
  #pragma unroll
  for (int i = 0; i < 16; i++) { float dd = v[i] - mu; var += dd * dd; }
  float rs = rsqrtf(var * (1.f / 16.f) + 1e-6f);
  const float* sc = part ? ks : qs;
  const float* bb = part ? kb : qb;
  uint16_t* dst = out + (size_t)n * 256 + part * 128 + h * 16;
  #pragma unroll
  for (int i = 0; i < 16; i++) dst[i] = f2bf((v[i] - mu) * rs * sc[i] + bb[i]);
}

// ---------------- FUSED edge kernel ----------------
// One wave per 16 sorted edges: MFMA dk|dv (16x512, K=64) -> in-register
// silu/attn/messages -> wave-level segmented sum per receiver, store (whole
// segment) or atomicAdd (window-straddling segment). No dkdv materialization.
__global__ __launch_bounds__(256) void k_edge_fused(
    const float* __restrict__ ea, const int* __restrict__ perm,
    const int* __restrict__ sndp, const int* __restrict__ rcvp,
    const int* __restrict__ off, const float4* __restrict__ edata,
    const uint16_t* __restrict__ WTdkv, const float* __restrict__ Bdkv,
    const uint16_t* __restrict__ qk_b, const uint16_t* __restrict__ qkv_b,
    const uint16_t* __restrict__ vec_b, float* __restrict__ xagg,
    float* __restrict__ vecagg) {
  int wid = blockIdx.x * 4 + (threadIdx.x >> 6);
  int w0 = wid * 16;
  if (w0 >= NE) return;
  int l = threadIdx.x & 63, d = l & 15, g = l >> 4;

  // ---- GEMM: acc[nf] = 16 edges x cols [16nf,16nf+16), K=64 ----
  f32x4 acc[32] = {};
  int erow = perm[w0 + d];                       // A-frag row = lane&15
  const float* arow = ea + (size_t)erow * 64 + g * 8;
  #pragma unroll
  for (int kk = 0; kk < 2; kk++) {
    float4 fa = *(const float4*)&arow[kk * 32];
    float4 fb = *(const float4*)&arow[kk * 32 + 4];
    union { bf16x8 v; uint32_t u[4]; } apk;
    apk.u[0] = pk2(fa.x, fa.y); apk.u[1] = pk2(fa.z, fa.w);
    apk.u[2] = pk2(fb.x, fb.y); apk.u[3] = pk2(fb.z, fb.w);
    #pragma unroll
    for (int nf = 0; nf < 32; nf++) {
      bf16x8 bv = *(const bf16x8*)&WTdkv[(size_t)(nf * 16 + d) * 64 + kk * 32 + g * 8];
      acc[nf] = __builtin_amdgcn_mfma_f32_16x16x32_bf16(apk.v, bv, acc[nf], 0, 0, 0);
    }
  }

  // ---- per-edge scalars (edge of (g,r) = w0 + 4g + r) ----
  int rcv_[4], snd_[4];
  float cut_[4], ev0[4], ev1[4], ev2[4];
  #pragma unroll
  for (int r = 0; r < 4; r++) {
    int e = w0 + 4 * g + r;
    rcv_[r] = rcvp[e]; snd_[r] = sndp[e];
    float4 ed = edata[e];
    ev0[r] = ed.x; ev1[r] = ed.y; ev2[r] = ed.z;
    cut_[r] = (ed.w < 5.f) ? 0.5f * (__cosf(ed.w * 0.628318530717958648f) + 1.f) : 0.f;
  }

  // ---- attn + messages per head (overwrite acc with messages) ----
  #pragma unroll
  for (int h = 0; h < 8; h++) {
    float bdk_ = Bdkv[h * 16 + d];
    float b0 = Bdkv[128 + h * 48 + d];
    float b1 = Bdkv[128 + h * 48 + 16 + d];
    float b2 = Bdkv[128 + h * 48 + 32 + d];
    float att[4];
    #pragma unroll
    for (int r = 0; r < 4; r++) {
      float dk = siluf(acc[h][r] + bdk_);
      float qv = bf2f(qk_b[(size_t)rcv_[r] * 256 + h * 16 + d]);
      float kv = bf2f(qk_b[(size_t)snd_[r] * 256 + 128 + h * 16 + d]);
      float t = qv * kv * dk;
      t += __shfl_xor(t, 1); t += __shfl_xor(t, 2);
      t += __shfl_xor(t, 4); t += __shfl_xor(t, 8);
      att[r] = siluf(t) * cut_[r];
    }
    #pragma unroll
    for (int r = 0; r < 4; r++) {
      float dv0 = siluf(acc[8 + 3 * h][r] + b0);
      float dv1 = siluf(acc[9 + 3 * h][r] + b1);
      float dv2 = siluf(acc[10 + 3 * h][r] + b2);
      const uint16_t* vrow = qkv_b + (size_t)snd_[r] * 640 + 256 + h * 48;
      float xm = bf2f(vrow[d]) * dv0 * att[r];
      float m1 = bf2f(vrow[16 + d]) * dv1;
      float m2 = bf2f(vrow[32 + d]) * dv2;
      const uint16_t* vecrow = vec_b + (size_t)snd_[r] * 384 + h * 16 + d;
      acc[h][r] = xm;
      acc[8 + 3 * h][r]  = bf2f(vecrow[0])   * m1 + m2 * ev0[r];
      acc[9 + 3 * h][r]  = bf2f(vecrow[128]) * m1 + m2 * ev1[r];
      acc[10 + 3 * h][r] = bf2f(vecrow[256]) * m1 + m2 * ev2[r];
    }
  }

  // ---- segmented reduce over receiver segments in this 16-edge window ----
  int w1 = w0 + 16;
  int i = w0;
  while (i < w1) {
    int n = rcvp[i];                    // wave-uniform
    int a = off[n], b = off[n + 1];
    int lo = i - w0;
    int hi = (b < w1 ? b : w1) - w0;
    bool whole = (a >= w0) && (b <= w1);
    #pragma unroll
    for (int f = 0; f < 32; f++) {
      float s = 0.f;
      #pragma unroll
      for (int r = 0; r < 4; r++) {
        int rr = 4 * g + r;
        s += (rr >= lo && rr < hi) ? acc[f][r] : 0.f;
      }
      s += __shfl_xor(s, 16);
      s += __shfl_xor(s, 32);
      if (g == (f & 3)) {
        float* dst;
        if (f < 8) {
          dst = &xagg[(size_t)n * 128 + f * 16 + d];
        } else {
          int hh = (f - 8) / 3, cc = (f - 8) % 3;
          dst = &vecagg[((size_t)n * 3 + cc) * 128 + hh * 16 + d];
        }
        if (whole) *dst = s; else atomicAdd(dst, s);
      }
    }
    i = (b > i) ? b : (i + 1);
  }
}

// ---------------- final: dx = vec_dot*o2+o3 ; dvec = vec3*o1 + vec_agg ----------------
__global__ void k_final(const float* __restrict__ o, const uint16_t* __restrict__ vp,
                        float* __restrict__ dx, float* __restrict__ dvec) {
  int idx = blockIdx.x * 256 + threadIdx.x;
  if (idx >= NN * 128) return;
  int n = idx >> 7, j = idx & 127;
  const float* op = o + (size_t)n * 384;
  float o1 = op[j], o2 = op[128 + j], o3 = op[256 + j];
  const uint16_t* vpn = vp + (size_t)n * 3 * 384;
  float vd = 0.f;
  #pragma unroll
  for (int c = 0; c < 3; c++)
    vd += bf2f(vpn[c * 384 + j]) * bf2f(vpn[c * 384 + 128 + j]);
  dx[idx] = vd * o2 + o3;
  #pragma unroll
  for (int c = 0; c < 3; c++) {
    size_t vi = ((size_t)n * 3 + c) * 128 + j;
    dvec[vi] = bf2f(vpn[c * 384 + 256 + j]) * o1 + dvec[vi];
  }
}

static inline int cdiv_i(long long a, long long b) { return (int)((a + b - 1) / b); }

extern "C" void kernel_launch(void* const* d_in, const int* in_sizes, int n_in,
                              void* d_out, int out_size, void* d_ws, size_t ws_size,
                              hipStream_t stream) {
  const float* x    = (const float*)d_in[0];
  const float* vec  = (const float*)d_in[1];
  const float* ew   = (const float*)d_in[2];
  const float* ea   = (const float*)d_in[3];
  const float* evec = (const float*)d_in[4];
  const int*   snd  = (const int*)d_in[5];
  const int*   rcv  = (const int*)d_in[6];
  const float* ln_s = (const float*)d_in[7];
  const float* ln_b = (const float*)d_in[8];
  const float* Wq = (const float*)d_in[9];   const float* bq = (const float*)d_in[10];
  const float* Wk = (const float*)d_in[11];  const float* bk = (const float*)d_in[12];
  const float* Wv = (const float*)d_in[13];  const float* bv = (const float*)d_in[14];
  const float* Wvec = (const float*)d_in[15];
  const float* Wdk = (const float*)d_in[16]; const float* bdk = (const float*)d_in[17];
  const float* Wdv = (const float*)d_in[18]; const float* bdv = (const float*)d_in[19];
  const float* Wo = (const float*)d_in[20];  const float* bo = (const float*)d_in[21];
  const float* qln_s = (const float*)d_in[22]; const float* qln_b = (const float*)d_in[23];
  const float* kln_s = (const float*)d_in[24]; const float* kln_b = (const float*)d_in[25];
  (void)in_sizes; (void)n_in; (void)out_size; (void)ws_size;

  uint8_t* p = (uint8_t*)d_ws;
  auto alloc = [&](size_t bytes) -> uint8_t* {
    uint8_t* r = p; p += (bytes + 255) & ~(size_t)255; return r;
  };
  uint16_t* WTqkv = (uint16_t*)alloc(640 * 128 * 2);
  float*    Bqkv  = (float*)alloc(640 * 4);
  uint16_t* WTvec = (uint16_t*)alloc(384 * 128 * 2);
  uint16_t* WTdkv = (uint16_t*)alloc(512 * 64 * 2);
  float*    Bdkv  = (float*)alloc(512 * 4);
  uint16_t* WTo   = (uint16_t*)alloc(384 * 128 * 2);
  int*      deg   = (int*)alloc(NN * 4);
  int*      off   = (int*)alloc((NN + 1) * 4);
  int*      cur   = (int*)alloc(NN * 4);
  int*      bsum  = (int*)alloc(256 * 4);
  int*      perm  = (int*)alloc((size_t)NE * 4);
  int*      sndp  = (int*)alloc((size_t)NE * 4);
  int*      rcvp  = (int*)alloc((size_t)NE * 4);
  float4*   edata = (float4*)alloc((size_t)NE * 16);
  uint16_t* xn_b  = (uint16_t*)alloc((size_t)NN * 128 * 2);
  uint16_t* qkv_b = (uint16_t*)alloc((size_t)NN * 640 * 2);
  uint16_t* qk_b  = (uint16_t*)alloc((size_t)NN * 256 * 2);
  uint16_t* vec_b = (uint16_t*)alloc((size_t)NN * 3 * 128 * 2);
  uint16_t* vp    = (uint16_t*)alloc((size_t)NN * 3 * 384 * 2);
  float*    o     = (float*)alloc((size_t)NN * 384 * 4);
  uint16_t* xagg_b = (uint16_t*)alloc((size_t)NN * 128 * 2);

  float* xagg   = (float*)d_out;
  float* vecagg = (float*)d_out + (size_t)NN * 128;

  hipMemsetAsync(d_out, 0, (size_t)out_size * 4, stream);

  // ---- weights prep ----
  k_transpose_cast<<<cdiv_i(128 * 128, 256), 256, 0, stream>>>(Wq, WTqkv, 128, 128);
  k_transpose_cast<<<cdiv_i(128 * 128, 256), 256, 0, stream>>>(Wk, WTqkv + 128 * 128, 128, 128);
  k_transpose_cast<<<cdiv_i(384 * 128, 256), 256, 0, stream>>>(Wv, WTqkv + 256 * 128, 128, 384);
  k_transpose_cast<<<cdiv_i(384 * 128, 256), 256, 0, stream>>>(Wvec, WTvec, 128, 384);
  k_transpose_cast<<<cdiv_i(128 * 64, 256), 256, 0, stream>>>(Wdk, WTdkv, 64, 128);
  k_transpose_cast<<<cdiv_i(384 * 64, 256), 256, 0, stream>>>(Wdv, WTdkv + 128 * 64, 64, 384);
  k_transpose_cast<<<cdiv_i(384 * 128, 256), 256, 0, stream>>>(Wo, WTo, 128, 384);
  k_bias_concat<<<3, 256, 0, stream>>>(bq, bk, bv, bdk, bdv, Bqkv, Bdkv);

  // ---- edge sort by receiver ----
  int NSB = cdiv_i(NN, 256);
  hipMemsetAsync(deg, 0, NN * 4, stream);
  k_hist<<<cdiv_i(NE, 256), 256, 0, stream>>>(rcv, deg);
  k_scan1<<<NSB, 256, 0, stream>>>(deg, bsum);
  k_scan2<<<1, 64, 0, stream>>>(bsum, NSB, off);
  k_scan3<<<NSB, 256, 0, stream>>>(deg, bsum, off, cur);
  k_scatter<<<cdiv_i(NE, 256), 256, 0, stream>>>(rcv, cur, perm);
  k_permute<<<cdiv_i(NE, 256), 256, 0, stream>>>(perm, snd, rcv, ew, evec, sndp, rcvp, edata);

  // ---- node pre ----
  k_ln_cast<<<cdiv_i((long long)NN * 64, 256), 256, 0, stream>>>(x, ln_s, ln_b, xn_b);
  k_cast_bf16<<<cdiv_i((long long)NN * 3 * 64, 256), 256, 0, stream>>>(vec, vec_b, NN * 3 * 64);

  // qkv = xn @ [Wq|Wk|Wv] + b  (bf16 out)
  { dim3 g(640 / 128, cdiv_i(NN, 128));
    k_gemm<128, true, false><<<g, 256, 0, stream>>>(xn_b, WTqkv, Bqkv, qkv_b, NN, 640); }
  k_headln<<<cdiv_i((long long)NN * 16, 256), 256, 0, stream>>>(qkv_b, qln_s, qln_b, kln_s, kln_b, qk_b);

  // vp = vec @ Wvec (bf16 out)
  { dim3 g(384 / 128, cdiv_i((long long)NN * 3, 128));
    k_gemm<128, true, false><<<g, 256, 0, stream>>>(vec_b, WTvec, nullptr, vp, NN * 3, 384); }

  // ---- fused edge phase: dkdv GEMM + attn + message + aggregation ----
  k_edge_fused<<<NE / 64, 256, 0, stream>>>(ea, perm, sndp, rcvp, off, edata, WTdkv,
                                            Bdkv, qk_b, qkv_b, vec_b, xagg, vecagg);

  // o = x_agg @ Wo + bo
  k_cast_bf16<<<cdiv_i((long long)NN * 64, 256), 256, 0, stream>>>(xagg, xagg_b, NN * 64);
  { dim3 g(384 / 128, cdiv_i(NN, 128));
    k_gemm<128, false, false><<<g, 256, 0, stream>>>(xagg_b, WTo, bo, o, NN, 384); }

  // outputs
  k_final<<<cdiv_i((long long)NN * 128, 256), 256, 0, stream>>>(o, vp, xagg, vecagg);
}

// Round 5
// 614.527 us; speedup vs baseline: 1.6040x; 1.6040x over previous
//
#include <hip/hip_runtime.h>
#include <stdint.h>

#define NN 20000
#define NE 200000
// H=128, NH=8, HD=16, RBF=64

typedef __attribute__((ext_vector_type(8))) short bf16x8;
typedef __attribute__((ext_vector_type(4))) float f32x4;

__device__ __forceinline__ float bf2f(uint32_t u) {
  union { uint32_t i; float f; } v; v.i = u << 16; return v.f;
}
__device__ __forceinline__ uint16_t f2bf(float f) {
  union { float f; uint32_t i; } v; v.f = f;
  return (uint16_t)((v.i + 0x7fffu + ((v.i >> 16) & 1u)) >> 16);
}
__device__ __forceinline__ uint32_t pk2(float lo, float hi) {
  return (uint32_t)f2bf(lo) | ((uint32_t)f2bf(hi) << 16);
}
__device__ __forceinline__ float siluf(float x) { return x / (1.f + __expf(-x)); }

// ---------------- prep kernels ----------------

__global__ void k_transpose_cast(const float* __restrict__ src, uint16_t* __restrict__ dst,
                                 int K, int C) {
  int idx = blockIdx.x * 256 + threadIdx.x;
  if (idx >= K * C) return;
  int c = idx / K, k = idx - c * K;
  dst[idx] = f2bf(src[(size_t)k * C + c]);
}

__global__ void k_bias_concat(const float* __restrict__ bq, const float* __restrict__ bk,
                              const float* __restrict__ bv, const float* __restrict__ bdk,
                              const float* __restrict__ bdv, float* __restrict__ Bqkv,
                              float* __restrict__ Bdkv) {
  int t = blockIdx.x * 256 + threadIdx.x;
  if (t < 640) Bqkv[t] = (t < 128) ? bq[t] : ((t < 256) ? bk[t - 128] : bv[t - 256]);
  if (t < 512) Bdkv[t] = (t < 128) ? bdk[t] : bdv[t - 128];
}

__global__ void k_ln_cast(const float* __restrict__ x, const float* __restrict__ s,
                          const float* __restrict__ b, uint16_t* __restrict__ out) {
  int gt = blockIdx.x * 256 + threadIdx.x;
  int node = gt >> 6, lane = gt & 63;
  if (node >= NN) return;
  const float* row = x + (size_t)node * 128;
  float2 v = *(const float2*)&row[lane * 2];
  float sum = v.x + v.y, sq = v.x * v.x + v.y * v.y;
  #pragma unroll
  for (int off = 32; off; off >>= 1) { sum += __shfl_xor(sum, off); sq += __shfl_xor(sq, off); }
  float mu = sum * (1.f / 128.f);
  float var = sq * (1.f / 128.f) - mu * mu;
  float rs = rsqrtf(var + 1e-6f);
  float o0 = (v.x - mu) * rs * s[lane * 2] + b[lane * 2];
  float o1 = (v.y - mu) * rs * s[lane * 2 + 1] + b[lane * 2 + 1];
  ((uint32_t*)out)[(size_t)node * 64 + lane] = pk2(o0, o1);
}

__global__ void k_cast_bf16(const float* __restrict__ src, uint16_t* __restrict__ dst, int npairs) {
  int i = blockIdx.x * 256 + threadIdx.x;
  if (i >= npairs) return;
  float2 v = ((const float2*)src)[i];
  ((uint32_t*)dst)[i] = pk2(v.x, v.y);
}

// ---------------- edge sort by receiver (counting sort, parallel scan) ----------------
__global__ void k_hist(const int* __restrict__ rcv, int* __restrict__ deg) {
  int e = blockIdx.x * 256 + threadIdx.x;
  if (e < NE) atomicAdd(&deg[rcv[e]], 1);
}

__global__ void k_scan1(const int* __restrict__ deg, int* __restrict__ bsum) {
  __shared__ int ws[4];
  int i = blockIdx.x * 256 + threadIdx.x;
  int x = (i < NN) ? deg[i] : 0;
  #pragma unroll
  for (int d = 32; d; d >>= 1) x += __shfl_xor(x, d);
  if ((threadIdx.x & 63) == 0) ws[threadIdx.x >> 6] = x;
  __syncthreads();
  if (threadIdx.x == 0) bsum[blockIdx.x] = ws[0] + ws[1] + ws[2] + ws[3];
}

__global__ void k_scan2(int* __restrict__ bsum, int nb, int* __restrict__ off) {
  int lane = threadIdx.x;
  int carry = 0;
  for (int base = 0; base < nb; base += 64) {
    int i = base + lane;
    int x = (i < nb) ? bsum[i] : 0;
    int v = x;
    #pragma unroll
    for (int d = 1; d < 64; d <<= 1) { int y = __shfl_up(v, d); if (lane >= d) v += y; }
    if (i < nb) bsum[i] = carry + v - x;
    carry += __shfl(v, 63);
  }
  if (lane == 0) off[NN] = carry;
}

__global__ void k_scan3(const int* __restrict__ deg, const int* __restrict__ bsum,
                        int* __restrict__ off, int* __restrict__ cur) {
  __shared__ int ws[4];
  int t = threadIdx.x, lane = t & 63, w = t >> 6;
  int i = blockIdx.x * 256 + t;
  int x = (i < NN) ? deg[i] : 0;
  int v = x;
  #pragma unroll
  for (int d = 1; d < 64; d <<= 1) { int y = __shfl_up(v, d); if (lane >= d) v += y; }
  if (lane == 63) ws[w] = v;
  __syncthreads();
  int wadd = 0;
  for (int j = 0; j < w; j++) wadd += ws[j];
  int excl = bsum[blockIdx.x] + wadd + v - x;
  if (i < NN) { off[i] = excl; cur[i] = excl; }
}

__global__ void k_scatter(const int* __restrict__ rcv, int* __restrict__ cur,
                          int* __restrict__ perm) {
  int e = blockIdx.x * 256 + threadIdx.x;
  if (e >= NE) return;
  int pos = atomicAdd(&cur[rcv[e]], 1);
  perm[pos] = e;
}

// gather+cast edge_attr rows in permuted order; also permute snd/rcv and
// pack (evec.xyz, cutoff(ew)) into edata
__global__ void k_permute(const float* __restrict__ ea, const int* __restrict__ perm,
                          const int* __restrict__ snd, const int* __restrict__ rcv,
                          const float* __restrict__ ew, const float* __restrict__ evec,
                          uint16_t* __restrict__ ea_perm, int* __restrict__ sndp,
                          int* __restrict__ rcvp, float4* __restrict__ edata) {
  int idx = blockIdx.x * 256 + threadIdx.x;   // 16 threads per edge
  if (idx >= NE * 16) return;
  int i = idx >> 4, j = idx & 15;
  int e = perm[i];
  float4 v = *(const float4*)&ea[(size_t)e * 64 + j * 4];
  uint2 o;
  o.x = pk2(v.x, v.y);
  o.y = pk2(v.z, v.w);
  *(uint2*)&ea_perm[(size_t)i * 64 + j * 4] = o;
  if (j == 0) {
    sndp[i] = snd[e];
    rcvp[i] = rcv[e];
    float w = ew[e];
    float cut = (w < 5.f) ? 0.5f * (__cosf(w * 0.628318530717958648f) + 1.f) : 0.f;
    edata[i] = make_float4(evec[e * 3], evec[e * 3 + 1], evec[e * 3 + 2], cut);
  }
}

// ---------------- bf16 MFMA GEMM: C = act(A @ BT^T + bias) ----------------
template <int KTOT, bool OUT_BF16, bool SILU>
__global__ __launch_bounds__(256) void k_gemm(const uint16_t* __restrict__ A,
                                              const uint16_t* __restrict__ BT,
                                              const float* __restrict__ bias,
                                              void* __restrict__ Cout, int M, int Fo) {
  __shared__ __align__(16) uint16_t As[128 * 72];
  __shared__ __align__(16) uint16_t Bs[128 * 72];
  int t = threadIdx.x;
  int l = t & 63;
  int row0 = blockIdx.y * 128, col0 = blockIdx.x * 128;
  int wm = ((t >> 6) >> 1) * 64, wn = ((t >> 6) & 1) * 64;
  f32x4 acc[4][4] = {};
  for (int kt = 0; kt < KTOT; kt += 64) {
    __syncthreads();
    #pragma unroll
    for (int i = 0; i < 4; i++) {
      int c = i * 256 + t;
      int row = c >> 3, ko = (c & 7) * 8;
      uint4 av = make_uint4(0u, 0u, 0u, 0u);
      int gr = row0 + row;
      if (gr < M) av = *(const uint4*)&A[(size_t)gr * KTOT + kt + ko];
      *(uint4*)&As[row * 72 + ko] = av;
      uint4 bw = *(const uint4*)&BT[(size_t)(col0 + row) * KTOT + kt + ko];
      *(uint4*)&Bs[row * 72 + ko] = bw;
    }
    __syncthreads();
    #pragma unroll
    for (int kk = 0; kk < 64; kk += 32) {
      bf16x8 af[4], bfr[4];
      #pragma unroll
      for (int mf = 0; mf < 4; mf++)
        af[mf] = *(const bf16x8*)&As[(wm + mf * 16 + (l & 15)) * 72 + (l >> 4) * 8 + kk];
      #pragma unroll
      for (int nf = 0; nf < 4; nf++)
        bfr[nf] = *(const bf16x8*)&Bs[(wn + nf * 16 + (l & 15)) * 72 + (l >> 4) * 8 + kk];
      #pragma unroll
      for (int mf = 0; mf < 4; mf++)
        #pragma unroll
        for (int nf = 0; nf < 4; nf++)
          acc[mf][nf] = __builtin_amdgcn_mfma_f32_16x16x32_bf16(af[mf], bfr[nf], acc[mf][nf], 0, 0, 0);
    }
  }
  float* Cf = (float*)Cout;
  uint16_t* Cb = (uint16_t*)Cout;
  #pragma unroll
  for (int mf = 0; mf < 4; mf++) {
    #pragma unroll
    for (int r = 0; r < 4; r++) {
      int grow = row0 + wm + mf * 16 + (l >> 4) * 4 + r;
      if (grow >= M) continue;
      #pragma unroll
      for (int nf = 0; nf < 4; nf++) {
        int gcol = col0 + wn + nf * 16 + (l & 15);
        float v = acc[mf][nf][r];
        if (bias) v += bias[gcol];
        if (SILU) v = siluf(v);
        if (OUT_BF16) Cb[(size_t)grow * Fo + gcol] = f2bf(v);
        else          Cf[(size_t)grow * Fo + gcol] = v;
      }
    }
  }
}

// ---------------- edge GEMM over chunk [off[n0], off[n1]) ----------------
// blockIdx.x == 0 : dk columns (0..127) -> fused attn epilogue, writes attnb[E,8]
// blockIdx.x >= 1 : dv columns -> silu -> bf16 dvb [Mcap, 384]
__global__ __launch_bounds__(256) void k_edge_gemm(
    const uint16_t* __restrict__ Aperm, const int* __restrict__ pbeg,
    const int* __restrict__ pend, const uint16_t* __restrict__ BT,
    const float* __restrict__ Bdkv, const int* __restrict__ sndp,
    const int* __restrict__ rcvp, const float4* __restrict__ edata,
    const uint16_t* __restrict__ qk_b, float* __restrict__ attnb,
    uint16_t* __restrict__ dvb, int Mcap) {
  int e0 = pbeg[0];
  int M = pend[0] - e0;
  if (M > Mcap) M = Mcap;
  int row0 = blockIdx.y * 128, col0 = blockIdx.x * 128;
  if (row0 >= M) return;
  const uint16_t* A = Aperm + (size_t)e0 * 64;
  __shared__ __align__(16) uint16_t As[128 * 72];
  __shared__ __align__(16) uint16_t Bs[128 * 72];
  int t = threadIdx.x;
  int l = t & 63;
  int wm = ((t >> 6) >> 1) * 64, wn = ((t >> 6) & 1) * 64;
  f32x4 acc[4][4] = {};
  {
    #pragma unroll
    for (int i = 0; i < 4; i++) {
      int c = i * 256 + t;
      int row = c >> 3, ko = (c & 7) * 8;
      uint4 av = make_uint4(0u, 0u, 0u, 0u);
      if (row0 + row < M) av = *(const uint4*)&A[(size_t)(row0 + row) * 64 + ko];
      *(uint4*)&As[row * 72 + ko] = av;
      uint4 bw = *(const uint4*)&BT[(size_t)(col0 + row) * 64 + ko];
      *(uint4*)&Bs[row * 72 + ko] = bw;
    }
    __syncthreads();
    #pragma unroll
    for (int kk = 0; kk < 64; kk += 32) {
      bf16x8 af[4], bfr[4];
      #pragma unroll
      for (int mf = 0; mf < 4; mf++)
        af[mf] = *(const bf16x8*)&As[(wm + mf * 16 + (l & 15)) * 72 + (l >> 4) * 8 + kk];
      #pragma unroll
      for (int nf = 0; nf < 4; nf++)
        bfr[nf] = *(const bf16x8*)&Bs[(wn + nf * 16 + (l & 15)) * 72 + (l >> 4) * 8 + kk];
      #pragma unroll
      for (int mf = 0; mf < 4; mf++)
        #pragma unroll
        for (int nf = 0; nf < 4; nf++)
          acc[mf][nf] = __builtin_amdgcn_mfma_f32_16x16x32_bf16(af[mf], bfr[nf], acc[mf][nf], 0, 0, 0);
    }
  }
  int d = l & 15;
  if (col0 == 0) {
    // ---- fused attn epilogue: attn[e][h] = silu(sum_d q*k*silu(dk+b)) * cut ----
    #pragma unroll
    for (int mf = 0; mf < 4; mf++) {
      #pragma unroll
      for (int r = 0; r < 4; r++) {
        int lrow = row0 + wm + mf * 16 + (l >> 4) * 4 + r;
        if (lrow >= M) continue;
        int ge = e0 + lrow;
        int rn = rcvp[ge], sn = sndp[ge];
        float cut = edata[ge].w;
        #pragma unroll
        for (int nf = 0; nf < 4; nf++) {
          int h = (wn >> 4) + nf;    // wn in {0,64} -> heads 0..3 / 4..7
          float dk = siluf(acc[mf][nf][r] + Bdkv[h * 16 + d]);
          float qv = bf2f(qk_b[(size_t)rn * 256 + h * 16 + d]);
          float kv = bf2f(qk_b[(size_t)sn * 256 + 128 + h * 16 + d]);
          float tt = qv * kv * dk;
          tt += __shfl_xor(tt, 1); tt += __shfl_xor(tt, 2);
          tt += __shfl_xor(tt, 4); tt += __shfl_xor(tt, 8);
          if (d == 0) attnb[(size_t)ge * 8 + h] = siluf(tt) * cut;
        }
      }
    }
  } else {
    int cb = col0 - 128;
    #pragma unroll
    for (int mf = 0; mf < 4; mf++) {
      #pragma unroll
      for (int r = 0; r < 4; r++) {
        int grow = row0 + wm + mf * 16 + (l >> 4) * 4 + r;
        if (grow >= M) continue;
        #pragma unroll
        for (int nf = 0; nf < 4; nf++) {
          int gcol = wn + nf * 16 + d;
          float v = siluf(acc[mf][nf][r] + Bdkv[col0 + gcol]);
          dvb[(size_t)grow * 384 + cb + gcol] = f2bf(v);
        }
      }
    }
  }
}

// ---------------- per-head LN on q/k (bf16 in/out) ----------------
__global__ void k_headln(const uint16_t* __restrict__ qkv, const float* __restrict__ qs,
                         const float* __restrict__ qb, const float* __restrict__ ks,
                         const float* __restrict__ kb, uint16_t* __restrict__ out) {
  int idx = blockIdx.x * 256 + threadIdx.x;
  if (idx >= NN * 16) return;
  int n = idx >> 4, ph = idx & 15, part = ph >> 3, h = ph & 7;
  const uint16_t* src = qkv + (size_t)n * 640 + part * 128 + h * 16;
  float v[16], sum = 0.f;
  #pragma unroll
  for (int i = 0; i < 16; i++) { v[i] = bf2f(src[i]); sum += v[i]; }
  float mu = sum * (1.f / 16.f), var = 0.f;
  #pragma unroll
  for (int i = 0; i < 16; i++) { float dd = v[i] - mu; var += dd * dd; }
  float rs = rsqrtf(var * (1.f / 16.f) + 1e-6f);
  const float* sc = part ? ks : qs;
  const float* bb = part ? kb : qb;
  uint16_t* dst = out + (size_t)n * 256 + part * 128 + h * 16;
  #pragma unroll
  for (int i = 0; i < 16; i++) dst[i] = f2bf((v[i] - mu) * rs * sc[i] + bb[i]);
}

// ---------------- message + segment aggregation (no atomics, attn precomputed) ----------------
__global__ __launch_bounds__(128) void k_agg(
    const uint16_t* __restrict__ dvb, const float* __restrict__ attnb,
    const int* __restrict__ off, const int* __restrict__ sndp,
    const float4* __restrict__ edata, const uint16_t* __restrict__ qkv_b,
    const uint16_t* __restrict__ vec_b, float* __restrict__ xagg,
    float* __restrict__ vecagg, int n0, int n1, int Mcap) {
  int n = n0 + blockIdx.x;
  if (n >= n1) return;
  int hd = threadIdx.x, h = hd >> 4, d = hd & 15;
  int i0 = off[n], i1 = off[n + 1];
  int ebase = off[n0];
  int vb = h * 48 + d;
  float ax = 0.f, a0 = 0.f, a1 = 0.f, a2 = 0.f;
  for (int i = i0; i < i1; i++) {
    int li = i - ebase;
    if (li >= Mcap) break;
    int s = sndp[i];
    float a = attnb[(size_t)i * 8 + h];
    const uint16_t* row = dvb + (size_t)li * 384;
    float dv0 = bf2f(row[vb]), dv1 = bf2f(row[16 + vb]), dv2 = bf2f(row[32 + vb]);
    const uint16_t* vsp = qkv_b + (size_t)s * 640 + 256 + vb;
    float m1 = bf2f(vsp[16]) * dv1;
    float m2 = bf2f(vsp[32]) * dv2;
    ax += bf2f(vsp[0]) * dv0 * a;
    float4 ed = edata[i];
    const uint16_t* vv = vec_b + (size_t)s * 384;
    a0 += bf2f(vv[hd]) * m1 + m2 * ed.x;
    a1 += bf2f(vv[128 + hd]) * m1 + m2 * ed.y;
    a2 += bf2f(vv[256 + hd]) * m1 + m2 * ed.z;
  }
  xagg[(size_t)n * 128 + hd] = ax;
  vecagg[((size_t)n * 3 + 0) * 128 + hd] = a0;
  vecagg[((size_t)n * 3 + 1) * 128 + hd] = a1;
  vecagg[((size_t)n * 3 + 2) * 128 + hd] = a2;
}

// ---------------- final ----------------
__global__ void k_final(const float* __restrict__ o, const uint16_t* __restrict__ vp,
                        float* __restrict__ dx, float* __restrict__ dvec) {
  int idx = blockIdx.x * 256 + threadIdx.x;
  if (idx >= NN * 128) return;
  int n = idx >> 7, j = idx & 127;
  const float* op = o + (size_t)n * 384;
  float o1 = op[j], o2 = op[128 + j], o3 = op[256 + j];
  const uint16_t* vpn = vp + (size_t)n * 3 * 384;
  float vd = 0.f;
  #pragma unroll
  for (int c = 0; c < 3; c++)
    vd += bf2f(vpn[c * 384 + j]) * bf2f(vpn[c * 384 + 128 + j]);
  dx[idx] = vd * o2 + o3;
  #pragma unroll
  for (int c = 0; c < 3; c++) {
    size_t vi = ((size_t)n * 3 + c) * 128 + j;
    dvec[vi] = bf2f(vpn[c * 384 + 256 + j]) * o1 + dvec[vi];
  }
}

static inline int cdiv_i(long long a, long long b) { return (int)((a + b - 1) / b); }

extern "C" void kernel_launch(void* const* d_in, const int* in_sizes, int n_in,
                              void* d_out, int out_size, void* d_ws, size_t ws_size,
                              hipStream_t stream) {
  const float* x    = (const float*)d_in[0];
  const float* vec  = (const float*)d_in[1];
  const float* ew   = (const float*)d_in[2];
  const float* ea   = (const float*)d_in[3];
  const float* evec = (const float*)d_in[4];
  const int*   snd  = (const int*)d_in[5];
  const int*   rcv  = (const int*)d_in[6];
  const float* ln_s = (const float*)d_in[7];
  const float* ln_b = (const float*)d_in[8];
  const float* Wq = (const float*)d_in[9];   const float* bq = (const float*)d_in[10];
  const float* Wk = (const float*)d_in[11];  const float* bk = (const float*)d_in[12];
  const float* Wv = (const float*)d_in[13];  const float* bv = (const float*)d_in[14];
  const float* Wvec = (const float*)d_in[15];
  const float* Wdk = (const float*)d_in[16]; const float* bdk = (const float*)d_in[17];
  const float* Wdv = (const float*)d_in[18]; const float* bdv = (const float*)d_in[19];
  const float* Wo = (const float*)d_in[20];  const float* bo = (const float*)d_in[21];
  const float* qln_s = (const float*)d_in[22]; const float* qln_b = (const float*)d_in[23];
  const float* kln_s = (const float*)d_in[24]; const float* kln_b = (const float*)d_in[25];
  (void)in_sizes; (void)n_in; (void)out_size;

  uint8_t* p = (uint8_t*)d_ws;
  auto alloc = [&](size_t bytes) -> uint8_t* {
    uint8_t* r = p; p += (bytes + 255) & ~(size_t)255; return r;
  };
  uint16_t* WTqkv = (uint16_t*)alloc(640 * 128 * 2);
  float*    Bqkv  = (float*)alloc(640 * 4);
  uint16_t* WTvec = (uint16_t*)alloc(384 * 128 * 2);
  uint16_t* WTdkv = (uint16_t*)alloc(512 * 64 * 2);
  float*    Bdkv  = (float*)alloc(512 * 4);
  uint16_t* WTo   = (uint16_t*)alloc(384 * 128 * 2);
  int*      deg   = (int*)alloc(NN * 4);
  int*      off   = (int*)alloc((NN + 1) * 4);
  int*      cur   = (int*)alloc(NN * 4);
  int*      bsum  = (int*)alloc(256 * 4);
  int*      perm  = (int*)alloc((size_t)NE * 4);
  int*      sndp  = (int*)alloc((size_t)NE * 4);
  int*      rcvp  = (int*)alloc((size_t)NE * 4);
  float4*   edata = (float4*)alloc((size_t)NE * 16);
  uint16_t* xn_b  = (uint16_t*)alloc((size_t)NN * 128 * 2);
  uint16_t* qkv_b = (uint16_t*)alloc((size_t)NN * 640 * 2);
  uint16_t* qk_b  = (uint16_t*)alloc((size_t)NN * 256 * 2);
  uint16_t* vec_b = (uint16_t*)alloc((size_t)NN * 3 * 128 * 2);
  uint16_t* vp    = (uint16_t*)alloc((size_t)NN * 3 * 384 * 2);
  uint16_t* ea_perm = (uint16_t*)alloc((size_t)NE * 64 * 2);
  float*    attnb = (float*)alloc((size_t)NE * 8 * 4);
  float*    o      = (float*)alloc((size_t)NN * 384 * 4);
  uint16_t* xagg_b = (uint16_t*)alloc((size_t)NN * 128 * 2);
  size_t fixed = (size_t)(p - (uint8_t*)d_ws);

  // adaptive node-chunking for the dv buffer (768 B/edge)
  int nchunk = 1;
  long long CHmax = NE;
  for (nchunk = 1; nchunk <= 64; nchunk++) {
    long long base = (NE + nchunk - 1) / nchunk;
    CHmax = (nchunk == 1) ? (long long)NE : base + base / 4;   // 1.25x margin
    if (fixed + (size_t)CHmax * 768 + 4096 <= ws_size) break;
  }
  uint16_t* dvb = (uint16_t*)alloc((size_t)CHmax * 768);
  int NB = cdiv_i(NN, nchunk);

  float* xagg   = (float*)d_out;
  float* vecagg = (float*)d_out + (size_t)NN * 128;

  // ---- weights prep ----
  k_transpose_cast<<<cdiv_i(128 * 128, 256), 256, 0, stream>>>(Wq, WTqkv, 128, 128);
  k_transpose_cast<<<cdiv_i(128 * 128, 256), 256, 0, stream>>>(Wk, WTqkv + 128 * 128, 128, 128);
  k_transpose_cast<<<cdiv_i(384 * 128, 256), 256, 0, stream>>>(Wv, WTqkv + 256 * 128, 128, 384);
  k_transpose_cast<<<cdiv_i(384 * 128, 256), 256, 0, stream>>>(Wvec, WTvec, 128, 384);
  k_transpose_cast<<<cdiv_i(128 * 64, 256), 256, 0, stream>>>(Wdk, WTdkv, 64, 128);
  k_transpose_cast<<<cdiv_i(384 * 64, 256), 256, 0, stream>>>(Wdv, WTdkv + 128 * 64, 64, 384);
  k_transpose_cast<<<cdiv_i(384 * 128, 256), 256, 0, stream>>>(Wo, WTo, 128, 384);
  k_bias_concat<<<3, 256, 0, stream>>>(bq, bk, bv, bdk, bdv, Bqkv, Bdkv);

  // ---- edge sort by receiver ----
  int NSB = cdiv_i(NN, 256);
  hipMemsetAsync(deg, 0, NN * 4, stream);
  k_hist<<<cdiv_i(NE, 256), 256, 0, stream>>>(rcv, deg);
  k_scan1<<<NSB, 256, 0, stream>>>(deg, bsum);
  k_scan2<<<1, 64, 0, stream>>>(bsum, NSB, off);
  k_scan3<<<NSB, 256, 0, stream>>>(deg, bsum, off, cur);
  k_scatter<<<cdiv_i(NE, 256), 256, 0, stream>>>(rcv, cur, perm);
  k_permute<<<cdiv_i((long long)NE * 16, 256), 256, 0, stream>>>(ea, perm, snd, rcv, ew, evec,
                                                                 ea_perm, sndp, rcvp, edata);

  // ---- node pre ----
  k_ln_cast<<<cdiv_i((long long)NN * 64, 256), 256, 0, stream>>>(x, ln_s, ln_b, xn_b);
  k_cast_bf16<<<cdiv_i((long long)NN * 3 * 64, 256), 256, 0, stream>>>(vec, vec_b, NN * 3 * 64);

  // qkv = xn @ [Wq|Wk|Wv] + b  (bf16 out)
  { dim3 g(640 / 128, cdiv_i(NN, 128));
    k_gemm<128, true, false><<<g, 256, 0, stream>>>(xn_b, WTqkv, Bqkv, qkv_b, NN, 640); }
  k_headln<<<cdiv_i((long long)NN * 16, 256), 256, 0, stream>>>(qkv_b, qln_s, qln_b, kln_s, kln_b, qk_b);

  // vp = vec @ Wvec (bf16 out)
  { dim3 g(384 / 128, cdiv_i((long long)NN * 3, 128));
    k_gemm<128, true, false><<<g, 256, 0, stream>>>(vec_b, WTvec, nullptr, vp, NN * 3, 384); }

  // ---- edge phase: per node-chunk, dk-attn + dv GEMM then aggregation ----
  for (int c = 0; c < nchunk; c++) {
    int nlo = c * NB, nhi = (c + 1) * NB; if (nhi > NN) nhi = NN;
    if (nlo >= nhi) break;
    dim3 g(4, cdiv_i(CHmax, 128));
    k_edge_gemm<<<g, 256, 0, stream>>>(ea_perm, &off[nlo], &off[nhi], WTdkv, Bdkv,
                                       sndp, rcvp, edata, qk_b, attnb, dvb, (int)CHmax);
    k_agg<<<nhi - nlo, 128, 0, stream>>>(dvb, attnb, off, sndp, edata, qkv_b,
                                         vec_b, xagg, vecagg, nlo, nhi, (int)CHmax);
  }

  // o = x_agg @ Wo + bo
  k_cast_bf16<<<cdiv_i((long long)NN * 64, 256), 256, 0, stream>>>(xagg, xagg_b, NN * 64);
  { dim3 g(384 / 128, cdiv_i(NN, 128));
    k_gemm<128, false, false><<<g, 256, 0, stream>>>(xagg_b, WTo, bo, o, NN, 384); }

  // outputs
  k_final<<<cdiv_i((long long)NN * 128, 256), 256, 0, stream>>>(o, vp, xagg, vecagg);
}

// Round 6
// 414.373 us; speedup vs baseline: 2.3788x; 1.4830x over previous
//
#include <hip/hip_runtime.h>
#include <stdint.h>

#define NN 20000
#define NE 200000
// H=128, NH=8, HD=16, RBF=64

typedef __attribute__((ext_vector_type(8))) short bf16x8;
typedef __attribute__((ext_vector_type(4))) float f32x4;

__device__ __forceinline__ float bf2f(uint32_t u) {
  union { uint32_t i; float f; } v; v.i = u << 16; return v.f;
}
__device__ __forceinline__ uint16_t f2bf(float f) {
  union { float f; uint32_t i; } v; v.f = f;
  return (uint16_t)((v.i + 0x7fffu + ((v.i >> 16) & 1u)) >> 16);
}
__device__ __forceinline__ uint32_t pk2(float lo, float hi) {
  return (uint32_t)f2bf(lo) | ((uint32_t)f2bf(hi) << 16);
}
__device__ __forceinline__ float siluf(float x) { return x / (1.f + __expf(-x)); }

// ---------------- consolidated weight prep (one launch) ----------------
__global__ void k_prep(const float* __restrict__ Wq, const float* __restrict__ Wk,
                       const float* __restrict__ Wv, const float* __restrict__ Wvec,
                       const float* __restrict__ Wdk, const float* __restrict__ Wdv,
                       const float* __restrict__ Wo, const float* __restrict__ bq,
                       const float* __restrict__ bk, const float* __restrict__ bv,
                       const float* __restrict__ bdk, const float* __restrict__ bdv,
                       uint16_t* __restrict__ WTqkv, uint16_t* __restrict__ WTvec,
                       uint16_t* __restrict__ WTdkv, uint16_t* __restrict__ WTo,
                       float* __restrict__ Bqkv, float* __restrict__ Bdkv) {
  int idx = blockIdx.x * 256 + threadIdx.x;
  if (idx < 81920) {                       // WTqkv [640][128]
    int j = idx;
    float v;
    if (j < 16384)      { int c = j >> 7, k = j & 127; v = Wq[k * 128 + c]; }
    else if (j < 32768) { j -= 16384; int c = j >> 7, k = j & 127; v = Wk[k * 128 + c]; }
    else                { j -= 32768; int c = j >> 7, k = j & 127; v = Wv[k * 384 + c]; }
    WTqkv[idx] = f2bf(v);
    return;
  }
  idx -= 81920;
  if (idx < 49152) {                       // WTvec [384][128]
    int c = idx >> 7, k = idx & 127;
    WTvec[idx] = f2bf(Wvec[k * 384 + c]);
    return;
  }
  idx -= 49152;
  if (idx < 32768) {                       // WTdkv [512][64]
    float v;
    if (idx < 8192) { int c = idx >> 6, k = idx & 63; v = Wdk[k * 128 + c]; }
    else            { int j = idx - 8192; int c = j >> 6, k = j & 63; v = Wdv[k * 384 + c]; }
    WTdkv[idx] = f2bf(v);
    return;
  }
  idx -= 32768;
  if (idx < 49152) {                       // WTo [384][128]
    int c = idx >> 7, k = idx & 127;
    WTo[idx] = f2bf(Wo[k * 384 + c]);
    return;
  }
  idx -= 49152;
  if (idx < 640) Bqkv[idx] = (idx < 128) ? bq[idx] : ((idx < 256) ? bk[idx - 128] : bv[idx - 256]);
  else if (idx < 1152) { int t = idx - 640; Bdkv[t] = (t < 128) ? bdk[t] : bdv[t - 128]; }
}

// ---------------- node pre: LN(x)->bf16  +  cast vec->bf16 (one launch) ----------------
__global__ void k_node_pre(const float* __restrict__ x, const float* __restrict__ s,
                           const float* __restrict__ b, const float* __restrict__ vec,
                           uint16_t* __restrict__ xn_b, uint16_t* __restrict__ vec_b) {
  if (blockIdx.x < 5000) {                 // LN part: NN*64 threads
    int gt = blockIdx.x * 256 + threadIdx.x;
    int node = gt >> 6, lane = gt & 63;
    if (node >= NN) return;
    const float* row = x + (size_t)node * 128;
    float2 v = *(const float2*)&row[lane * 2];
    float sum = v.x + v.y, sq = v.x * v.x + v.y * v.y;
    #pragma unroll
    for (int off = 32; off; off >>= 1) { sum += __shfl_xor(sum, off); sq += __shfl_xor(sq, off); }
    float mu = sum * (1.f / 128.f);
    float var = sq * (1.f / 128.f) - mu * mu;
    float rs = rsqrtf(var + 1e-6f);
    float o0 = (v.x - mu) * rs * s[lane * 2] + b[lane * 2];
    float o1 = (v.y - mu) * rs * s[lane * 2 + 1] + b[lane * 2 + 1];
    ((uint32_t*)xn_b)[(size_t)node * 64 + lane] = pk2(o0, o1);
  } else {                                 // vec cast: NN*3*64 pairs
    int i = (blockIdx.x - 5000) * 256 + threadIdx.x;
    if (i >= NN * 3 * 64) return;
    float2 v = ((const float2*)vec)[i];
    ((uint32_t*)vec_b)[i] = pk2(v.x, v.y);
  }
}

__global__ void k_cast_bf16(const float* __restrict__ src, uint16_t* __restrict__ dst, int npairs) {
  int i = blockIdx.x * 256 + threadIdx.x;
  if (i >= npairs) return;
  float2 v = ((const float2*)src)[i];
  ((uint32_t*)dst)[i] = pk2(v.x, v.y);
}

// ---------------- edge sort by receiver (counting sort, parallel scan) ----------------
__global__ void k_hist(const int* __restrict__ rcv, int* __restrict__ deg) {
  int e = blockIdx.x * 256 + threadIdx.x;
  if (e < NE) atomicAdd(&deg[rcv[e]], 1);
}

__global__ void k_scan1(const int* __restrict__ deg, int* __restrict__ bsum) {
  __shared__ int ws[4];
  int i = blockIdx.x * 256 + threadIdx.x;
  int x = (i < NN) ? deg[i] : 0;
  #pragma unroll
  for (int d = 32; d; d >>= 1) x += __shfl_xor(x, d);
  if ((threadIdx.x & 63) == 0) ws[threadIdx.x >> 6] = x;
  __syncthreads();
  if (threadIdx.x == 0) bsum[blockIdx.x] = ws[0] + ws[1] + ws[2] + ws[3];
}

__global__ void k_scan2(int* __restrict__ bsum, int nb, int* __restrict__ off) {
  int lane = threadIdx.x;
  int carry = 0;
  for (int base = 0; base < nb; base += 64) {
    int i = base + lane;
    int x = (i < nb) ? bsum[i] : 0;
    int v = x;
    #pragma unroll
    for (int d = 1; d < 64; d <<= 1) { int y = __shfl_up(v, d); if (lane >= d) v += y; }
    if (i < nb) bsum[i] = carry + v - x;
    carry += __shfl(v, 63);
  }
  if (lane == 0) off[NN] = carry;
}

__global__ void k_scan3(const int* __restrict__ deg, const int* __restrict__ bsum,
                        int* __restrict__ off, int* __restrict__ cur) {
  __shared__ int ws[4];
  int t = threadIdx.x, lane = t & 63, w = t >> 6;
  int i = blockIdx.x * 256 + t;
  int x = (i < NN) ? deg[i] : 0;
  int v = x;
  #pragma unroll
  for (int d = 1; d < 64; d <<= 1) { int y = __shfl_up(v, d); if (lane >= d) v += y; }
  if (lane == 63) ws[w] = v;
  __syncthreads();
  int wadd = 0;
  for (int j = 0; j < w; j++) wadd += ws[j];
  int excl = bsum[blockIdx.x] + wadd + v - x;
  if (i < NN) { off[i] = excl; cur[i] = excl; }
}

__global__ void k_scatter(const int* __restrict__ rcv, int* __restrict__ cur,
                          int* __restrict__ perm) {
  int e = blockIdx.x * 256 + threadIdx.x;
  if (e >= NE) return;
  int pos = atomicAdd(&cur[rcv[e]], 1);
  perm[pos] = e;
}

// gather+cast edge_attr rows in permuted order; also permute snd/rcv and
// pack (evec.xyz, cutoff(ew)) into edata
__global__ void k_permute(const float* __restrict__ ea, const int* __restrict__ perm,
                          const int* __restrict__ snd, const int* __restrict__ rcv,
                          const float* __restrict__ ew, const float* __restrict__ evec,
                          uint16_t* __restrict__ ea_perm, int* __restrict__ sndp,
                          int* __restrict__ rcvp, float4* __restrict__ edata) {
  int idx = blockIdx.x * 256 + threadIdx.x;   // 16 threads per edge
  if (idx >= NE * 16) return;
  int i = idx >> 4, j = idx & 15;
  int e = perm[i];
  float4 v = *(const float4*)&ea[(size_t)e * 64 + j * 4];
  uint2 o;
  o.x = pk2(v.x, v.y);
  o.y = pk2(v.z, v.w);
  *(uint2*)&ea_perm[(size_t)i * 64 + j * 4] = o;
  if (j == 0) {
    sndp[i] = snd[e];
    rcvp[i] = rcv[e];
    float w = ew[e];
    float cut = (w < 5.f) ? 0.5f * (__cosf(w * 0.628318530717958648f) + 1.f) : 0.f;
    edata[i] = make_float4(evec[e * 3], evec[e * 3 + 1], evec[e * 3 + 2], cut);
  }
}

// ---------------- bf16 MFMA GEMM: C = act(A @ BT^T + bias) ----------------
template <int KTOT, bool OUT_BF16, bool SILU>
__global__ __launch_bounds__(256) void k_gemm(const uint16_t* __restrict__ A,
                                              const uint16_t* __restrict__ BT,
                                              const float* __restrict__ bias,
                                              void* __restrict__ Cout, int M, int Fo) {
  __shared__ __align__(16) uint16_t As[128 * 72];
  __shared__ __align__(16) uint16_t Bs[128 * 72];
  int t = threadIdx.x;
  int l = t & 63;
  int row0 = blockIdx.y * 128, col0 = blockIdx.x * 128;
  int wm = ((t >> 6) >> 1) * 64, wn = ((t >> 6) & 1) * 64;
  f32x4 acc[4][4] = {};
  for (int kt = 0; kt < KTOT; kt += 64) {
    __syncthreads();
    #pragma unroll
    for (int i = 0; i < 4; i++) {
      int c = i * 256 + t;
      int row = c >> 3, ko = (c & 7) * 8;
      uint4 av = make_uint4(0u, 0u, 0u, 0u);
      int gr = row0 + row;
      if (gr < M) av = *(const uint4*)&A[(size_t)gr * KTOT + kt + ko];
      *(uint4*)&As[row * 72 + ko] = av;
      uint4 bw = *(const uint4*)&BT[(size_t)(col0 + row) * KTOT + kt + ko];
      *(uint4*)&Bs[row * 72 + ko] = bw;
    }
    __syncthreads();
    #pragma unroll
    for (int kk = 0; kk < 64; kk += 32) {
      bf16x8 af[4], bfr[4];
      #pragma unroll
      for (int mf = 0; mf < 4; mf++)
        af[mf] = *(const bf16x8*)&As[(wm + mf * 16 + (l & 15)) * 72 + (l >> 4) * 8 + kk];
      #pragma unroll
      for (int nf = 0; nf < 4; nf++)
        bfr[nf] = *(const bf16x8*)&Bs[(wn + nf * 16 + (l & 15)) * 72 + (l >> 4) * 8 + kk];
      #pragma unroll
      for (int mf = 0; mf < 4; mf++)
        #pragma unroll
        for (int nf = 0; nf < 4; nf++)
          acc[mf][nf] = __builtin_amdgcn_mfma_f32_16x16x32_bf16(af[mf], bfr[nf], acc[mf][nf], 0, 0, 0);
    }
  }
  float* Cf = (float*)Cout;
  uint16_t* Cb = (uint16_t*)Cout;
  #pragma unroll
  for (int mf = 0; mf < 4; mf++) {
    #pragma unroll
    for (int r = 0; r < 4; r++) {
      int grow = row0 + wm + mf * 16 + (l >> 4) * 4 + r;
      if (grow >= M) continue;
      #pragma unroll
      for (int nf = 0; nf < 4; nf++) {
        int gcol = col0 + wn + nf * 16 + (l & 15);
        float v = acc[mf][nf][r];
        if (bias) v += bias[gcol];
        if (SILU) v = siluf(v);
        if (OUT_BF16) Cb[(size_t)grow * Fo + gcol] = f2bf(v);
        else          Cf[(size_t)grow * Fo + gcol] = v;
      }
    }
  }
}

// ---------------- edge GEMM over chunk [off[n0], off[n1]) ----------------
// MFMA as in R3, then silu tile -> LDS bf16. col0==0: per-(edge,head) attn
// (contiguous 32B q/k gathers, in-register dot, no shfl) -> attnb; dk never
// written to HBM. col0>=1: uint4 re-read of LDS -> 16B coalesced dv stores.
__global__ __launch_bounds__(256) void k_edge_gemm(
    const uint16_t* __restrict__ Aperm, const int* __restrict__ pbeg,
    const int* __restrict__ pend, const uint16_t* __restrict__ BT,
    const float* __restrict__ Bdkv, const int* __restrict__ sndp,
    const int* __restrict__ rcvp, const float4* __restrict__ edata,
    const uint16_t* __restrict__ qk_b, float* __restrict__ attnb,
    uint16_t* __restrict__ dvb, int Mcap) {
  __shared__ __align__(16) uint16_t sbuf[2 * 128 * 72];  // As|Bs, then C-tile [128][136]
  uint16_t* As = sbuf;
  uint16_t* Bs = sbuf + 128 * 72;
  int e0 = pbeg[0];
  int M = pend[0] - e0;
  if (M > Mcap) M = Mcap;
  int row0 = blockIdx.y * 128, col0 = blockIdx.x * 128;
  if (row0 >= M) return;
  const uint16_t* A = Aperm + (size_t)e0 * 64;
  int t = threadIdx.x;
  int l = t & 63;
  int wm = ((t >> 6) >> 1) * 64, wn = ((t >> 6) & 1) * 64;
  f32x4 acc[4][4] = {};
  {
    #pragma unroll
    for (int i = 0; i < 4; i++) {
      int c = i * 256 + t;
      int row = c >> 3, ko = (c & 7) * 8;
      uint4 av = make_uint4(0u, 0u, 0u, 0u);
      if (row0 + row < M) av = *(const uint4*)&A[(size_t)(row0 + row) * 64 + ko];
      *(uint4*)&As[row * 72 + ko] = av;
      uint4 bw = *(const uint4*)&BT[(size_t)(col0 + row) * 64 + ko];
      *(uint4*)&Bs[row * 72 + ko] = bw;
    }
    __syncthreads();
    #pragma unroll
    for (int kk = 0; kk < 64; kk += 32) {
      bf16x8 af[4], bfr[4];
      #pragma unroll
      for (int mf = 0; mf < 4; mf++)
        af[mf] = *(const bf16x8*)&As[(wm + mf * 16 + (l & 15)) * 72 + (l >> 4) * 8 + kk];
      #pragma unroll
      for (int nf = 0; nf < 4; nf++)
        bfr[nf] = *(const bf16x8*)&Bs[(wn + nf * 16 + (l & 15)) * 72 + (l >> 4) * 8 + kk];
      #pragma unroll
      for (int mf = 0; mf < 4; mf++)
        #pragma unroll
        for (int nf = 0; nf < 4; nf++)
          acc[mf][nf] = __builtin_amdgcn_mfma_f32_16x16x32_bf16(af[mf], bfr[nf], acc[mf][nf], 0, 0, 0);
    }
  }
  // silu(acc + bias) -> LDS bf16 tile [128][136]
  __syncthreads();
  #pragma unroll
  for (int mf = 0; mf < 4; mf++) {
    #pragma unroll
    for (int r = 0; r < 4; r++) {
      int lrow = wm + mf * 16 + (l >> 4) * 4 + r;
      #pragma unroll
      for (int nf = 0; nf < 4; nf++) {
        int lcol = wn + nf * 16 + (l & 15);
        sbuf[lrow * 136 + lcol] = f2bf(siluf(acc[mf][nf][r] + Bdkv[col0 + lcol]));
      }
    }
  }
  __syncthreads();
  if (col0 == 0) {
    // attn: thread -> (edge el, head h), 4 passes
    #pragma unroll
    for (int pass = 0; pass < 4; pass++) {
      int el = pass * 32 + (t >> 3), h = t & 7;
      int lrow = row0 + el;
      if (lrow >= M) continue;
      int ge = e0 + lrow;
      int rn = rcvp[ge], sn = sndp[ge];
      const uint32_t* dkp = (const uint32_t*)&sbuf[el * 136 + h * 16];
      const uint32_t* qp = (const uint32_t*)(qk_b + (size_t)rn * 256 + h * 16);
      const uint32_t* kp = (const uint32_t*)(qk_b + (size_t)sn * 256 + 128 + h * 16);
      float dot = 0.f;
      #pragma unroll
      for (int j = 0; j < 8; j++) {
        uint32_t qu = qp[j], ku = kp[j], du = dkp[j];
        dot += bf2f(qu & 0xffffu) * bf2f(ku & 0xffffu) * bf2f(du & 0xffffu)
             + bf2f(qu >> 16) * bf2f(ku >> 16) * bf2f(du >> 16);
      }
      attnb[(size_t)ge * 8 + h] = siluf(dot) * edata[ge].w;
    }
  } else {
    int cb = col0 - 128;
    #pragma unroll
    for (int pass = 0; pass < 8; pass++) {
      int chunk = pass * 256 + t;
      int row = chunk >> 4, j = chunk & 15;
      int grow = row0 + row;
      if (grow >= M) continue;
      uint4 v = *(const uint4*)&sbuf[row * 136 + j * 8];
      *(uint4*)&dvb[(size_t)grow * 384 + cb + j * 8] = v;
    }
  }
}

// ---------------- per-head LN on q/k (bf16 in/out) ----------------
__global__ void k_headln(const uint16_t* __restrict__ qkv, const float* __restrict__ qs,
                         const float* __restrict__ qb, const float* __restrict__ ks,
                         const float* __restrict__ kb, uint16_t* __restrict__ out) {
  int idx = blockIdx.x * 256 + threadIdx.x;
  if (idx >= NN * 16) return;
  int n = idx >> 4, ph = idx & 15, part = ph >> 3, h = ph & 7;
  const uint16_t* src = qkv + (size_t)n * 640 + part * 128 + h * 16;
  float v[16], sum = 0.f;
  #pragma unroll
  for (int i = 0; i < 16; i++) { v[i] = bf2f(src[i]); sum += v[i]; }
  float mu = sum * (1.f / 16.f), var = 0.f;
  #pragma unroll
  for (int i = 0; i < 16; i++) { float dd = v[i] - mu; var += dd * dd; }
  float rs = rsqrtf(var * (1.f / 16.f) + 1e-6f);
  const float* sc = part ? ks : qs;
  const float* bb = part ? kb : qb;
  uint16_t* dst = out + (size_t)n * 256 + part * 128 + h * 16;
  #pragma unroll
  for (int i = 0; i < 16; i++) dst[i] = f2bf((v[i] - mu) * rs * sc[i] + bb[i]);
}

// ---------------- message + segment aggregation (no atomics, attn precomputed) ----------------
__global__ __launch_bounds__(128) void k_agg(
    const uint16_t* __restrict__ dvb, const float* __restrict__ attnb,
    const int* __restrict__ off, const int* __restrict__ sndp,
    const float4* __restrict__ edata, const uint16_t* __restrict__ qkv_b,
    const uint16_t* __restrict__ vec_b, float* __restrict__ xagg,
    float* __restrict__ vecagg, int n0, int n1, int Mcap) {
  int n = n0 + blockIdx.x;
  if (n >= n1) return;
  int hd = threadIdx.x, h = hd >> 4, d = hd & 15;
  int i0 = off[n], i1 = off[n + 1];
  int ebase = off[n0];
  int vb = h * 48 + d;
  float ax = 0.f, a0 = 0.f, a1 = 0.f, a2 = 0.f;
  for (int i = i0; i < i1; i++) {
    int li = i - ebase;
    if (li >= Mcap) break;
    int s = sndp[i];
    float a = attnb[(size_t)i * 8 + h];
    const uint16_t* row = dvb + (size_t)li * 384;
    float dv0 = bf2f(row[vb]), dv1 = bf2f(row[16 + vb]), dv2 = bf2f(row[32 + vb]);
    const uint16_t* vsp = qkv_b + (size_t)s * 640 + 256 + vb;
    float m1 = bf2f(vsp[16]) * dv1;
    float m2 = bf2f(vsp[32]) * dv2;
    ax += bf2f(vsp[0]) * dv0 * a;
    float4 ed = edata[i];
    const uint16_t* vv = vec_b + (size_t)s * 384;
    a0 += bf2f(vv[hd]) * m1 + m2 * ed.x;
    a1 += bf2f(vv[128 + hd]) * m1 + m2 * ed.y;
    a2 += bf2f(vv[256 + hd]) * m1 + m2 * ed.z;
  }
  xagg[(size_t)n * 128 + hd] = ax;
  vecagg[((size_t)n * 3 + 0) * 128 + hd] = a0;
  vecagg[((size_t)n * 3 + 1) * 128 + hd] = a1;
  vecagg[((size_t)n * 3 + 2) * 128 + hd] = a2;
}

// ---------------- final ----------------
__global__ void k_final(const float* __restrict__ o, const uint16_t* __restrict__ vp,
                        float* __restrict__ dx, float* __restrict__ dvec) {
  int idx = blockIdx.x * 256 + threadIdx.x;
  if (idx >= NN * 128) return;
  int n = idx >> 7, j = idx & 127;
  const float* op = o + (size_t)n * 384;
  float o1 = op[j], o2 = op[128 + j], o3 = op[256 + j];
  const uint16_t* vpn = vp + (size_t)n * 3 * 384;
  float vd = 0.f;
  #pragma unroll
  for (int c = 0; c < 3; c++)
    vd += bf2f(vpn[c * 384 + j]) * bf2f(vpn[c * 384 + 128 + j]);
  dx[idx] = vd * o2 + o3;
  #pragma unroll
  for (int c = 0; c < 3; c++) {
    size_t vi = ((size_t)n * 3 + c) * 128 + j;
    dvec[vi] = bf2f(vpn[c * 384 + 256 + j]) * o1 + dvec[vi];
  }
}

static inline int cdiv_i(long long a, long long b) { return (int)((a + b - 1) / b); }

extern "C" void kernel_launch(void* const* d_in, const int* in_sizes, int n_in,
                              void* d_out, int out_size, void* d_ws, size_t ws_size,
                              hipStream_t stream) {
  const float* x    = (const float*)d_in[0];
  const float* vec  = (const float*)d_in[1];
  const float* ew   = (const float*)d_in[2];
  const float* ea   = (const float*)d_in[3];
  const float* evec = (const float*)d_in[4];
  const int*   snd  = (const int*)d_in[5];
  const int*   rcv  = (const int*)d_in[6];
  const float* ln_s = (const float*)d_in[7];
  const float* ln_b = (const float*)d_in[8];
  const float* Wq = (const float*)d_in[9];   const float* bq = (const float*)d_in[10];
  const float* Wk = (const float*)d_in[11];  const float* bk = (const float*)d_in[12];
  const float* Wv = (const float*)d_in[13];  const float* bv = (const float*)d_in[14];
  const float* Wvec = (const float*)d_in[15];
  const float* Wdk = (const float*)d_in[16]; const float* bdk = (const float*)d_in[17];
  const float* Wdv = (const float*)d_in[18]; const float* bdv = (const float*)d_in[19];
  const float* Wo = (const float*)d_in[20];  const float* bo = (const float*)d_in[21];
  const float* qln_s = (const float*)d_in[22]; const float* qln_b = (const float*)d_in[23];
  const float* kln_s = (const float*)d_in[24]; const float* kln_b = (const float*)d_in[25];
  (void)in_sizes; (void)n_in; (void)out_size;

  uint8_t* p = (uint8_t*)d_ws;
  auto alloc = [&](size_t bytes) -> uint8_t* {
    uint8_t* r = p; p += (bytes + 255) & ~(size_t)255; return r;
  };
  uint16_t* WTqkv = (uint16_t*)alloc(640 * 128 * 2);
  float*    Bqkv  = (float*)alloc(640 * 4);
  uint16_t* WTvec = (uint16_t*)alloc(384 * 128 * 2);
  uint16_t* WTdkv = (uint16_t*)alloc(512 * 64 * 2);
  float*    Bdkv  = (float*)alloc(512 * 4);
  uint16_t* WTo   = (uint16_t*)alloc(384 * 128 * 2);
  int*      deg   = (int*)alloc(NN * 4);
  int*      off   = (int*)alloc((NN + 1) * 4);
  int*      cur   = (int*)alloc(NN * 4);
  int*      bsum  = (int*)alloc(256 * 4);
  int*      perm  = (int*)alloc((size_t)NE * 4);
  int*      sndp  = (int*)alloc((size_t)NE * 4);
  int*      rcvp  = (int*)alloc((size_t)NE * 4);
  float4*   edata = (float4*)alloc((size_t)NE * 16);
  uint16_t* xn_b  = (uint16_t*)alloc((size_t)NN * 128 * 2);
  uint16_t* qkv_b = (uint16_t*)alloc((size_t)NN * 640 * 2);
  uint16_t* qk_b  = (uint16_t*)alloc((size_t)NN * 256 * 2);
  uint16_t* vec_b = (uint16_t*)alloc((size_t)NN * 3 * 128 * 2);
  uint16_t* vp    = (uint16_t*)alloc((size_t)NN * 3 * 384 * 2);
  uint16_t* ea_perm = (uint16_t*)alloc((size_t)NE * 64 * 2);
  float*    attnb = (float*)alloc((size_t)NE * 8 * 4);
  float*    o      = (float*)alloc((size_t)NN * 384 * 4);
  uint16_t* xagg_b = (uint16_t*)alloc((size_t)NN * 128 * 2);
  size_t fixed = (size_t)(p - (uint8_t*)d_ws);

  // adaptive node-chunking for the dv buffer (768 B/edge)
  int nchunk = 1;
  long long CHmax = NE;
  for (nchunk = 1; nchunk <= 64; nchunk++) {
    long long base = (NE + nchunk - 1) / nchunk;
    CHmax = (nchunk == 1) ? (long long)NE : base + base / 4;   // 1.25x margin
    if (fixed + (size_t)CHmax * 768 + 4096 <= ws_size) break;
  }
  uint16_t* dvb = (uint16_t*)alloc((size_t)CHmax * 768);
  int NB = cdiv_i(NN, nchunk);

  float* xagg   = (float*)d_out;
  float* vecagg = (float*)d_out + (size_t)NN * 128;

  // ---- weights prep (1 launch) ----
  k_prep<<<cdiv_i(81920 + 49152 + 32768 + 49152 + 1152, 256), 256, 0, stream>>>(
      Wq, Wk, Wv, Wvec, Wdk, Wdv, Wo, bq, bk, bv, bdk, bdv,
      WTqkv, WTvec, WTdkv, WTo, Bqkv, Bdkv);

  // ---- edge sort by receiver ----
  int NSB = cdiv_i(NN, 256);
  hipMemsetAsync(deg, 0, NN * 4, stream);
  k_hist<<<cdiv_i(NE, 256), 256, 0, stream>>>(rcv, deg);
  k_scan1<<<NSB, 256, 0, stream>>>(deg, bsum);
  k_scan2<<<1, 64, 0, stream>>>(bsum, NSB, off);
  k_scan3<<<NSB, 256, 0, stream>>>(deg, bsum, off, cur);
  k_scatter<<<cdiv_i(NE, 256), 256, 0, stream>>>(rcv, cur, perm);
  k_permute<<<cdiv_i((long long)NE * 16, 256), 256, 0, stream>>>(ea, perm, snd, rcv, ew, evec,
                                                                 ea_perm, sndp, rcvp, edata);

  // ---- node pre (1 launch) ----
  k_node_pre<<<5000 + cdiv_i((long long)NN * 3 * 64, 256), 256, 0, stream>>>(
      x, ln_s, ln_b, vec, xn_b, vec_b);

  // qkv = xn @ [Wq|Wk|Wv] + b  (bf16 out)
  { dim3 g(640 / 128, cdiv_i(NN, 128));
    k_gemm<128, true, false><<<g, 256, 0, stream>>>(xn_b, WTqkv, Bqkv, qkv_b, NN, 640); }
  k_headln<<<cdiv_i((long long)NN * 16, 256), 256, 0, stream>>>(qkv_b, qln_s, qln_b, kln_s, kln_b, qk_b);

  // vp = vec @ Wvec (bf16 out)
  { dim3 g(384 / 128, cdiv_i((long long)NN * 3, 128));
    k_gemm<128, true, false><<<g, 256, 0, stream>>>(vec_b, WTvec, nullptr, vp, NN * 3, 384); }

  // ---- edge phase: per node-chunk, dk-attn + dv GEMM then aggregation ----
  for (int c = 0; c < nchunk; c++) {
    int nlo = c * NB, nhi = (c + 1) * NB; if (nhi > NN) nhi = NN;
    if (nlo >= nhi) break;
    dim3 g(4, cdiv_i(CHmax, 128));
    k_edge_gemm<<<g, 256, 0, stream>>>(ea_perm, &off[nlo], &off[nhi], WTdkv, Bdkv,
                                       sndp, rcvp, edata, qk_b, attnb, dvb, (int)CHmax);
    k_agg<<<nhi - nlo, 128, 0, stream>>>(dvb, attnb, off, sndp, edata, qkv_b,
                                         vec_b, xagg, vecagg, nlo, nhi, (int)CHmax);
  }

  // o = x_agg @ Wo + bo
  k_cast_bf16<<<cdiv_i((long long)NN * 64, 256), 256, 0, stream>>>(xagg, xagg_b, NN * 64);
  { dim3 g(384 / 128, cdiv_i(NN, 128));
    k_gemm<128, false, false><<<g, 256, 0, stream>>>(xagg_b, WTo, bo, o, NN, 384); }

  // outputs
  k_final<<<cdiv_i((long long)NN * 128, 256), 256, 0, stream>>>(o, vp, xagg, vecagg);
}

// Round 7
// 369.691 us; speedup vs baseline: 2.6663x; 1.1209x over previous
//
#include <hip/hip_runtime.h>
#include <stdint.h>

#define NN 20000
#define NE 200000   // == 3125 * 64 exactly (k_edge_all assumes this)
// H=128, NH=8, HD=16, RBF=64

typedef __attribute__((ext_vector_type(8))) short bf16x8;
typedef __attribute__((ext_vector_type(4))) float f32x4;

__device__ __forceinline__ float bf2f(uint32_t u) {
  union { uint32_t i; float f; } v; v.i = u << 16; return v.f;
}
__device__ __forceinline__ uint16_t f2bf(float f) {
  union { float f; uint32_t i; } v; v.f = f;
  return (uint16_t)((v.i + 0x7fffu + ((v.i >> 16) & 1u)) >> 16);
}
__device__ __forceinline__ uint32_t pk2(float lo, float hi) {
  return (uint32_t)f2bf(lo) | ((uint32_t)f2bf(hi) << 16);
}
__device__ __forceinline__ float siluf(float x) { return x / (1.f + __expf(-x)); }
__device__ __forceinline__ float prod2(uint32_t q2, uint32_t k2, uint32_t d2) {
  return bf2f(q2 & 0xffffu) * bf2f(k2 & 0xffffu) * bf2f(d2 & 0xffffu)
       + bf2f(q2 >> 16) * bf2f(k2 >> 16) * bf2f(d2 >> 16);
}

// ---------------- consolidated weight prep (one launch) ----------------
// WTdkv2 is COLUMN-REORDERED: rows 0-127 = dk (h*16+d), 128-255 = dv part0 (xm),
// 256-383 = dv part1 (m1), 384-511 = dv part2 (m2). Bdkv2 reordered to match.
__global__ void k_prep(const float* __restrict__ Wq, const float* __restrict__ Wk,
                       const float* __restrict__ Wv, const float* __restrict__ Wvec,
                       const float* __restrict__ Wdk, const float* __restrict__ Wdv,
                       const float* __restrict__ Wo, const float* __restrict__ bq,
                       const float* __restrict__ bk, const float* __restrict__ bv,
                       const float* __restrict__ bdk, const float* __restrict__ bdv,
                       uint16_t* __restrict__ WTqkv, uint16_t* __restrict__ WTvec,
                       uint16_t* __restrict__ WTdkv2, uint16_t* __restrict__ WTo,
                       float* __restrict__ Bqkv, float* __restrict__ Bdkv2) {
  int idx = blockIdx.x * 256 + threadIdx.x;
  if (idx < 81920) {                       // WTqkv [640][128]
    int j = idx;
    float v;
    if (j < 16384)      { int c = j >> 7, k = j & 127; v = Wq[k * 128 + c]; }
    else if (j < 32768) { j -= 16384; int c = j >> 7, k = j & 127; v = Wk[k * 128 + c]; }
    else                { j -= 32768; int c = j >> 7, k = j & 127; v = Wv[k * 384 + c]; }
    WTqkv[idx] = f2bf(v);
    return;
  }
  idx -= 81920;
  if (idx < 49152) {                       // WTvec [384][128]
    int c = idx >> 7, k = idx & 127;
    WTvec[idx] = f2bf(Wvec[k * 384 + c]);
    return;
  }
  idx -= 49152;
  if (idx < 32768) {                       // WTdkv2 [512][64], reordered
    int rr = idx >> 6, k = idx & 63;
    float v;
    if (rr < 128) v = Wdk[k * 128 + rr];
    else {
      int j = rr - 128, p = j >> 7, hd = j & 127;
      int c = (hd >> 4) * 48 + p * 16 + (hd & 15);
      v = Wdv[k * 384 + c];
    }
    WTdkv2[idx] = f2bf(v);
    return;
  }
  idx -= 32768;
  if (idx < 49152) {                       // WTo [384][128]
    int c = idx >> 7, k = idx & 127;
    WTo[idx] = f2bf(Wo[k * 384 + c]);
    return;
  }
  idx -= 49152;
  if (idx < 640) Bqkv[idx] = (idx < 128) ? bq[idx] : ((idx < 256) ? bk[idx - 128] : bv[idx - 256]);
  else if (idx < 1152) {
    int t = idx - 640;
    if (t < 128) Bdkv2[t] = bdk[t];
    else {
      int j = t - 128, p = j >> 7, hd = j & 127;
      Bdkv2[t] = bdv[(hd >> 4) * 48 + p * 16 + (hd & 15)];
    }
  }
}

// ---------------- node pre: LN(x)->bf16  +  cast vec->bf16 (one launch) ----------------
__global__ void k_node_pre(const float* __restrict__ x, const float* __restrict__ s,
                           const float* __restrict__ b, const float* __restrict__ vec,
                           uint16_t* __restrict__ xn_b, uint16_t* __restrict__ vec_b) {
  if (blockIdx.x < 5000) {
    int gt = blockIdx.x * 256 + threadIdx.x;
    int node = gt >> 6, lane = gt & 63;
    if (node >= NN) return;
    const float* row = x + (size_t)node * 128;
    float2 v = *(const float2*)&row[lane * 2];
    float sum = v.x + v.y, sq = v.x * v.x + v.y * v.y;
    #pragma unroll
    for (int off = 32; off; off >>= 1) { sum += __shfl_xor(sum, off); sq += __shfl_xor(sq, off); }
    float mu = sum * (1.f / 128.f);
    float var = sq * (1.f / 128.f) - mu * mu;
    float rs = rsqrtf(var + 1e-6f);
    float o0 = (v.x - mu) * rs * s[lane * 2] + b[lane * 2];
    float o1 = (v.y - mu) * rs * s[lane * 2 + 1] + b[lane * 2 + 1];
    ((uint32_t*)xn_b)[(size_t)node * 64 + lane] = pk2(o0, o1);
  } else {
    int i = (blockIdx.x - 5000) * 256 + threadIdx.x;
    if (i >= NN * 3 * 64) return;
    float2 v = ((const float2*)vec)[i];
    ((uint32_t*)vec_b)[i] = pk2(v.x, v.y);
  }
}

__global__ void k_cast_bf16(const float* __restrict__ src, uint16_t* __restrict__ dst, int npairs) {
  int i = blockIdx.x * 256 + threadIdx.x;
  if (i >= npairs) return;
  float2 v = ((const float2*)src)[i];
  ((uint32_t*)dst)[i] = pk2(v.x, v.y);
}

// ---------------- edge sort by receiver (counting sort, parallel scan) ----------------
__global__ void k_hist(const int* __restrict__ rcv, int* __restrict__ deg) {
  int e = blockIdx.x * 256 + threadIdx.x;
  if (e < NE) atomicAdd(&deg[rcv[e]], 1);
}

__global__ void k_scan1(const int* __restrict__ deg, int* __restrict__ bsum) {
  __shared__ int ws[4];
  int i = blockIdx.x * 256 + threadIdx.x;
  int x = (i < NN) ? deg[i] : 0;
  #pragma unroll
  for (int d = 32; d; d >>= 1) x += __shfl_xor(x, d);
  if ((threadIdx.x & 63) == 0) ws[threadIdx.x >> 6] = x;
  __syncthreads();
  if (threadIdx.x == 0) bsum[blockIdx.x] = ws[0] + ws[1] + ws[2] + ws[3];
}

__global__ void k_scan2(int* __restrict__ bsum, int nb, int* __restrict__ off) {
  int lane = threadIdx.x;
  int carry = 0;
  for (int base = 0; base < nb; base += 64) {
    int i = base + lane;
    int x = (i < nb) ? bsum[i] : 0;
    int v = x;
    #pragma unroll
    for (int d = 1; d < 64; d <<= 1) { int y = __shfl_up(v, d); if (lane >= d) v += y; }
    if (i < nb) bsum[i] = carry + v - x;
    carry += __shfl(v, 63);
  }
  if (lane == 0) off[NN] = carry;
}

__global__ void k_scan3(const int* __restrict__ deg, const int* __restrict__ bsum,
                        int* __restrict__ off, int* __restrict__ cur) {
  __shared__ int ws[4];
  int t = threadIdx.x, lane = t & 63, w = t >> 6;
  int i = blockIdx.x * 256 + t;
  int x = (i < NN) ? deg[i] : 0;
  int v = x;
  #pragma unroll
  for (int d = 1; d < 64; d <<= 1) { int y = __shfl_up(v, d); if (lane >= d) v += y; }
  if (lane == 63) ws[w] = v;
  __syncthreads();
  int wadd = 0;
  for (int j = 0; j < w; j++) wadd += ws[j];
  int excl = bsum[blockIdx.x] + wadd + v - x;
  if (i < NN) { off[i] = excl; cur[i] = excl; }
}

__global__ void k_scatter(const int* __restrict__ rcv, int* __restrict__ cur,
                          int* __restrict__ perm) {
  int e = blockIdx.x * 256 + threadIdx.x;
  if (e >= NE) return;
  int pos = atomicAdd(&cur[rcv[e]], 1);
  perm[pos] = e;
}

// permute per-edge scalars into sorted order; cutoff precomputed into edata.w
__global__ void k_permute(const int* __restrict__ perm, const int* __restrict__ snd,
                          const int* __restrict__ rcv, const float* __restrict__ ew,
                          const float* __restrict__ evec, int* __restrict__ sndp,
                          int* __restrict__ rcvp, float4* __restrict__ edata) {
  int i = blockIdx.x * 256 + threadIdx.x;
  if (i >= NE) return;
  int e = perm[i];
  sndp[i] = snd[e];
  rcvp[i] = rcv[e];
  float w = ew[e];
  float cut = (w < 5.f) ? 0.5f * (__cosf(w * 0.628318530717958648f) + 1.f) : 0.f;
  edata[i] = make_float4(evec[e * 3], evec[e * 3 + 1], evec[e * 3 + 2], cut);
}

// ---------------- bf16 MFMA GEMM: C = act(A @ BT^T + bias) ----------------
template <int KTOT, bool OUT_BF16, bool SILU>
__global__ __launch_bounds__(256) void k_gemm(const uint16_t* __restrict__ A,
                                              const uint16_t* __restrict__ BT,
                                              const float* __restrict__ bias,
                                              void* __restrict__ Cout, int M, int Fo) {
  __shared__ __align__(16) uint16_t As[128 * 72];
  __shared__ __align__(16) uint16_t Bs[128 * 72];
  int t = threadIdx.x;
  int l = t & 63;
  int row0 = blockIdx.y * 128, col0 = blockIdx.x * 128;
  int wm = ((t >> 6) >> 1) * 64, wn = ((t >> 6) & 1) * 64;
  f32x4 acc[4][4] = {};
  for (int kt = 0; kt < KTOT; kt += 64) {
    __syncthreads();
    #pragma unroll
    for (int i = 0; i < 4; i++) {
      int c = i * 256 + t;
      int row = c >> 3, ko = (c & 7) * 8;
      uint4 av = make_uint4(0u, 0u, 0u, 0u);
      int gr = row0 + row;
      if (gr < M) av = *(const uint4*)&A[(size_t)gr * KTOT + kt + ko];
      *(uint4*)&As[row * 72 + ko] = av;
      uint4 bw = *(const uint4*)&BT[(size_t)(col0 + row) * KTOT + kt + ko];
      *(uint4*)&Bs[row * 72 + ko] = bw;
    }
    __syncthreads();
    #pragma unroll
    for (int kk = 0; kk < 64; kk += 32) {
      bf16x8 af[4], bfr[4];
      #pragma unroll
      for (int mf = 0; mf < 4; mf++)
        af[mf] = *(const bf16x8*)&As[(wm + mf * 16 + (l & 15)) * 72 + (l >> 4) * 8 + kk];
      #pragma unroll
      for (int nf = 0; nf < 4; nf++)
        bfr[nf] = *(const bf16x8*)&Bs[(wn + nf * 16 + (l & 15)) * 72 + (l >> 4) * 8 + kk];
      #pragma unroll
      for (int mf = 0; mf < 4; mf++)
        #pragma unroll
        for (int nf = 0; nf < 4; nf++)
          acc[mf][nf] = __builtin_amdgcn_mfma_f32_16x16x32_bf16(af[mf], bfr[nf], acc[mf][nf], 0, 0, 0);
    }
  }
  float* Cf = (float*)Cout;
  uint16_t* Cb = (uint16_t*)Cout;
  #pragma unroll
  for (int mf = 0; mf < 4; mf++) {
    #pragma unroll
    for (int r = 0; r < 4; r++) {
      int grow = row0 + wm + mf * 16 + (l >> 4) * 4 + r;
      if (grow >= M) continue;
      #pragma unroll
      for (int nf = 0; nf < 4; nf++) {
        int gcol = col0 + wn + nf * 16 + (l & 15);
        float v = acc[mf][nf][r];
        if (bias) v += bias[gcol];
        if (SILU) v = siluf(v);
        if (OUT_BF16) Cb[(size_t)grow * Fo + gcol] = f2bf(v);
        else          Cf[(size_t)grow * Fo + gcol] = v;
      }
    }
  }
}

// ---------------- per-head LN on q/k (bf16 in/out) ----------------
__global__ void k_headln(const uint16_t* __restrict__ qkv, const float* __restrict__ qs,
                         const float* __restrict__ qb, const float* __restrict__ ks,
                         const float* __restrict__ kb, uint16_t* __restrict__ out) {
  int idx = blockIdx.x * 256 + threadIdx.x;
  if (idx >= NN * 16) return;
  int n = idx >> 4, ph = idx & 15, part = ph >> 3, h = ph & 7;
  const uint16_t* src = qkv + (size_t)n * 640 + part * 128 + h * 16;
  float v[16], sum = 0.f;
  #pragma unroll
  for (int i = 0; i < 16; i++) { v[i] = bf2f(src[i]); sum += v[i]; }
  float mu = sum * (1.f / 16.f), var = 0.f;
  #pragma unroll
  for (int i = 0; i < 16; i++) { float dd = v[i] - mu; var += dd * dd; }
  float rs = rsqrtf(var * (1.f / 16.f) + 1e-6f);
  const float* sc = part ? ks : qs;
  const float* bb = part ? kb : qb;
  uint16_t* dst = out + (size_t)n * 256 + part * 128 + h * 16;
  #pragma unroll
  for (int i = 0; i < 16; i++) dst[i] = f2bf((v[i] - mu) * rs * sc[i] + bb[i]);
}

// ---------------- FULLY FUSED edge phase ----------------
// One 256-thread block per 64 sorted edges. A staged in LDS; B direct from
// L1/L2-resident WTdkv2 (column-reordered). Four MFMA passes (dk,xm,m1,m2),
// LDS silu tiles, then column-owner walks with segment flush (plain store for
// half-contained segments, atomicAdd for straddlers). No dv/attn in HBM.
__device__ __forceinline__ void mfma_cb(const uint16_t* As, const uint16_t* __restrict__ BT2,
                                        int cb, int wn, int l, f32x4 acc[4][2]) {
  #pragma unroll
  for (int kk = 0; kk < 2; kk++) {
    bf16x8 af[4];
    #pragma unroll
    for (int mf = 0; mf < 4; mf++)
      af[mf] = *(const bf16x8*)&As[(mf * 16 + (l & 15)) * 68 + (l >> 4) * 8 + kk * 32];
    #pragma unroll
    for (int nf = 0; nf < 2; nf++) {
      bf16x8 bv = *(const bf16x8*)&BT2[(size_t)(cb * 128 + wn + nf * 16 + (l & 15)) * 64 +
                                       (l >> 4) * 8 + kk * 32];
      #pragma unroll
      for (int mf = 0; mf < 4; mf++)
        acc[mf][nf] = __builtin_amdgcn_mfma_f32_16x16x32_bf16(af[mf], bv, acc[mf][nf], 0, 0, 0);
    }
  }
}

__device__ __forceinline__ void silu_store(uint16_t* mt, const float* bias_l, int cb,
                                           int wn, int l, f32x4 acc[4][2]) {
  #pragma unroll
  for (int mf = 0; mf < 4; mf++)
    #pragma unroll
    for (int r = 0; r < 4; r++) {
      int row = mf * 16 + (l >> 4) * 4 + r;
      #pragma unroll
      for (int nf = 0; nf < 2; nf++) {
        int c = wn + nf * 16 + (l & 15);
        mt[row * 140 + c] = f2bf(siluf(acc[mf][nf][r] + bias_l[cb * 128 + c]));
      }
    }
}

__global__ __launch_bounds__(256) void k_edge_all(
    const float* __restrict__ ea, const int* __restrict__ perm,
    const int* __restrict__ sndp, const int* __restrict__ rcvp,
    const int* __restrict__ off, const float4* __restrict__ edata,
    const uint16_t* __restrict__ WT2, const float* __restrict__ Bd2,
    const uint16_t* __restrict__ qk_b, const uint16_t* __restrict__ qkv_b,
    const uint16_t* __restrict__ vec_b, float* __restrict__ xagg,
    float* __restrict__ vecagg) {
  __shared__ __align__(16) uint16_t As[64 * 68];     // 8.5 KB
  __shared__ __align__(16) uint16_t mt1[64 * 140];   // 17.9 KB
  __shared__ __align__(16) uint16_t mt2[64 * 140];   // 17.9 KB
  __shared__ float attn_l[64 * 8];                   // 2 KB
  __shared__ float bias_l[512];                      // 2 KB
  __shared__ int sndl[64], rcvl[64], lo_g[64], hi_g[64];
  __shared__ float4 ed4[64];

  int e0 = blockIdx.x * 64;
  int t = threadIdx.x, l = t & 63, wn = (t >> 6) * 32;

  // ---- phase 0: meta + bias + A stage ----
  if (t < 64) {
    int e = e0 + t;
    int s = sndp[e], r = rcvp[e];
    sndl[t] = s; rcvl[t] = r;
    lo_g[t] = off[r]; hi_g[t] = off[r + 1];
    ed4[t] = edata[e];
  }
  bias_l[t] = Bd2[t];
  bias_l[t + 256] = Bd2[t + 256];
  {
    int row = t >> 2, qo = (t & 3) * 16;
    int pe = perm[e0 + row];
    const float* src = ea + (size_t)pe * 64 + qo;
    float4 f0 = *(const float4*)src;
    float4 f1 = *(const float4*)(src + 4);
    float4 f2 = *(const float4*)(src + 8);
    float4 f3 = *(const float4*)(src + 12);
    uint4 o0, o1;
    o0.x = pk2(f0.x, f0.y); o0.y = pk2(f0.z, f0.w);
    o0.z = pk2(f1.x, f1.y); o0.w = pk2(f1.z, f1.w);
    o1.x = pk2(f2.x, f2.y); o1.y = pk2(f2.z, f2.w);
    o1.z = pk2(f3.x, f3.y); o1.w = pk2(f3.z, f3.w);
    *(uint4*)&As[row * 68 + qo] = o0;
    *(uint4*)&As[row * 68 + qo + 8] = o1;
  }
  __syncthreads();

  // ---- cb0: dk -> mt1 ----
  { f32x4 acc[4][2] = {}; mfma_cb(As, WT2, 0, wn, l, acc); silu_store(mt1, bias_l, 0, wn, l, acc); }
  __syncthreads();

  // ---- attn: 512 (edge,head) tasks ----
  #pragma unroll
  for (int pass = 0; pass < 2; pass++) {
    int task = pass * 256 + t;
    int el = task >> 3, h = task & 7;
    int rn = rcvl[el], sn = sndl[el];
    const uint32_t* qp = (const uint32_t*)(qk_b + (size_t)rn * 256 + h * 16);
    const uint32_t* kp = (const uint32_t*)(qk_b + (size_t)sn * 256 + 128 + h * 16);
    const uint32_t* dp = (const uint32_t*)&mt1[el * 140 + h * 16];
    float dot = 0.f;
    #pragma unroll
    for (int j = 0; j < 8; j++) dot += prod2(qp[j], kp[j], dp[j]);
    attn_l[el * 8 + h] = siluf(dot) * ed4[el].w;
  }
  __syncthreads();

  // ---- cb1: xm-dv -> mt1 (dk no longer needed) ----
  { f32x4 acc[4][2] = {}; mfma_cb(As, WT2, 1, wn, l, acc); silu_store(mt1, bias_l, 1, wn, l, acc); }
  __syncthreads();

  // ---- xm walk: thread = (col, half of 32 edges) ----
  {
    int col = t & 127, half = t >> 7;
    int h0 = half * 32, h1 = h0 + 32;
    int voff = 256 + (col >> 4) * 48 + (col & 15);
    float accx = 0.f;
    #pragma unroll 4
    for (int i = h0; i < h1; i++) {
      int n = rcvl[i];
      float m = bf2f(mt1[i * 140 + col]);
      float a = attn_l[i * 8 + (col >> 4)];
      float v0 = bf2f(qkv_b[(size_t)sndl[i] * 640 + voff]);
      accx += v0 * m * a;
      if (i == h1 - 1 || rcvl[i + 1] != n) {
        float* dst = &xagg[(size_t)n * 128 + col];
        if (lo_g[i] >= e0 + h0 && hi_g[i] <= e0 + h1) *dst = accx;
        else atomicAdd(dst, accx);
        accx = 0.f;
      }
    }
  }
  __syncthreads();

  // ---- cb2: m1-dv -> mt1 ; cb3: m2-dv -> mt2 ----
  { f32x4 acc[4][2] = {}; mfma_cb(As, WT2, 2, wn, l, acc); silu_store(mt1, bias_l, 2, wn, l, acc); }
  { f32x4 acc[4][2] = {}; mfma_cb(As, WT2, 3, wn, l, acc); silu_store(mt2, bias_l, 3, wn, l, acc); }
  __syncthreads();

  // ---- m walk: vec_m = vec[s]*m1 + evec*m2, 3 outputs per col ----
  {
    int col = t & 127, half = t >> 7;
    int h0 = half * 32, h1 = h0 + 32;
    int v1o = 256 + (col >> 4) * 48 + 16 + (col & 15);
    float a0 = 0.f, a1 = 0.f, a2 = 0.f;
    #pragma unroll 4
    for (int i = h0; i < h1; i++) {
      int n = rcvl[i];
      int s = sndl[i];
      float m1d = bf2f(mt1[i * 140 + col]);
      float m2d = bf2f(mt2[i * 140 + col]);
      const uint16_t* vb = qkv_b + (size_t)s * 640 + v1o;
      float mm1 = bf2f(vb[0]) * m1d;
      float mm2 = bf2f(vb[16]) * m2d;
      const uint16_t* vv = vec_b + (size_t)s * 384 + col;
      float4 ev = ed4[i];
      a0 += bf2f(vv[0])   * mm1 + ev.x * mm2;
      a1 += bf2f(vv[128]) * mm1 + ev.y * mm2;
      a2 += bf2f(vv[256]) * mm1 + ev.z * mm2;
      if (i == h1 - 1 || rcvl[i + 1] != n) {
        float* d0 = &vecagg[((size_t)n * 3 + 0) * 128 + col];
        float* d1 = &vecagg[((size_t)n * 3 + 1) * 128 + col];
        float* d2 = &vecagg[((size_t)n * 3 + 2) * 128 + col];
        if (lo_g[i] >= e0 + h0 && hi_g[i] <= e0 + h1) { *d0 = a0; *d1 = a1; *d2 = a2; }
        else { atomicAdd(d0, a0); atomicAdd(d1, a1); atomicAdd(d2, a2); }
        a0 = a1 = a2 = 0.f;
      }
    }
  }
}

// ---------------- final ----------------
__global__ void k_final(const float* __restrict__ o, const uint16_t* __restrict__ vp,
                        float* __restrict__ dx, float* __restrict__ dvec) {
  int idx = blockIdx.x * 256 + threadIdx.x;
  if (idx >= NN * 128) return;
  int n = idx >> 7, j = idx & 127;
  const float* op = o + (size_t)n * 384;
  float o1 = op[j], o2 = op[128 + j], o3 = op[256 + j];
  const uint16_t* vpn = vp + (size_t)n * 3 * 384;
  float vd = 0.f;
  #pragma unroll
  for (int c = 0; c < 3; c++)
    vd += bf2f(vpn[c * 384 + j]) * bf2f(vpn[c * 384 + 128 + j]);
  dx[idx] = vd * o2 + o3;
  #pragma unroll
  for (int c = 0; c < 3; c++) {
    size_t vi = ((size_t)n * 3 + c) * 128 + j;
    dvec[vi] = bf2f(vpn[c * 384 + 256 + j]) * o1 + dvec[vi];
  }
}

static inline int cdiv_i(long long a, long long b) { return (int)((a + b - 1) / b); }

extern "C" void kernel_launch(void* const* d_in, const int* in_sizes, int n_in,
                              void* d_out, int out_size, void* d_ws, size_t ws_size,
                              hipStream_t stream) {
  const float* x    = (const float*)d_in[0];
  const float* vec  = (const float*)d_in[1];
  const float* ew   = (const float*)d_in[2];
  const float* ea   = (const float*)d_in[3];
  const float* evec = (const float*)d_in[4];
  const int*   snd  = (const int*)d_in[5];
  const int*   rcv  = (const int*)d_in[6];
  const float* ln_s = (const float*)d_in[7];
  const float* ln_b = (const float*)d_in[8];
  const float* Wq = (const float*)d_in[9];   const float* bq = (const float*)d_in[10];
  const float* Wk = (const float*)d_in[11];  const float* bk = (const float*)d_in[12];
  const float* Wv = (const float*)d_in[13];  const float* bv = (const float*)d_in[14];
  const float* Wvec = (const float*)d_in[15];
  const float* Wdk = (const float*)d_in[16]; const float* bdk = (const float*)d_in[17];
  const float* Wdv = (const float*)d_in[18]; const float* bdv = (const float*)d_in[19];
  const float* Wo = (const float*)d_in[20];  const float* bo = (const float*)d_in[21];
  const float* qln_s = (const float*)d_in[22]; const float* qln_b = (const float*)d_in[23];
  const float* kln_s = (const float*)d_in[24]; const float* kln_b = (const float*)d_in[25];
  (void)in_sizes; (void)n_in; (void)ws_size;

  uint8_t* p = (uint8_t*)d_ws;
  auto alloc = [&](size_t bytes) -> uint8_t* {
    uint8_t* r = p; p += (bytes + 255) & ~(size_t)255; return r;
  };
  uint16_t* WTqkv = (uint16_t*)alloc(640 * 128 * 2);
  float*    Bqkv  = (float*)alloc(640 * 4);
  uint16_t* WTvec = (uint16_t*)alloc(384 * 128 * 2);
  uint16_t* WTdkv = (uint16_t*)alloc(512 * 64 * 2);
  float*    Bdkv  = (float*)alloc(512 * 4);
  uint16_t* WTo   = (uint16_t*)alloc(384 * 128 * 2);
  int*      deg   = (int*)alloc(NN * 4);
  int*      off   = (int*)alloc((NN + 1) * 4);
  int*      cur   = (int*)alloc(NN * 4);
  int*      bsum  = (int*)alloc(256 * 4);
  int*      perm  = (int*)alloc((size_t)NE * 4);
  int*      sndp  = (int*)alloc((size_t)NE * 4);
  int*      rcvp  = (int*)alloc((size_t)NE * 4);
  float4*   edata = (float4*)alloc((size_t)NE * 16);
  uint16_t* xn_b  = (uint16_t*)alloc((size_t)NN * 128 * 2);
  uint16_t* qkv_b = (uint16_t*)alloc((size_t)NN * 640 * 2);
  uint16_t* qk_b  = (uint16_t*)alloc((size_t)NN * 256 * 2);
  uint16_t* vec_b = (uint16_t*)alloc((size_t)NN * 3 * 128 * 2);
  uint16_t* vp    = (uint16_t*)alloc((size_t)NN * 3 * 384 * 2);
  float*    o      = (float*)alloc((size_t)NN * 384 * 4);
  uint16_t* xagg_b = (uint16_t*)alloc((size_t)NN * 128 * 2);

  float* xagg   = (float*)d_out;
  float* vecagg = (float*)d_out + (size_t)NN * 128;

  hipMemsetAsync(d_out, 0, (size_t)out_size * 4, stream);

  // ---- weights prep (1 launch) ----
  k_prep<<<cdiv_i(81920 + 49152 + 32768 + 49152 + 1152, 256), 256, 0, stream>>>(
      Wq, Wk, Wv, Wvec, Wdk, Wdv, Wo, bq, bk, bv, bdk, bdv,
      WTqkv, WTvec, WTdkv, WTo, Bqkv, Bdkv);

  // ---- edge sort by receiver ----
  int NSB = cdiv_i(NN, 256);
  hipMemsetAsync(deg, 0, NN * 4, stream);
  k_hist<<<cdiv_i(NE, 256), 256, 0, stream>>>(rcv, deg);
  k_scan1<<<NSB, 256, 0, stream>>>(deg, bsum);
  k_scan2<<<1, 64, 0, stream>>>(bsum, NSB, off);
  k_scan3<<<NSB, 256, 0, stream>>>(deg, bsum, off, cur);
  k_scatter<<<cdiv_i(NE, 256), 256, 0, stream>>>(rcv, cur, perm);
  k_permute<<<cdiv_i(NE, 256), 256, 0, stream>>>(perm, snd, rcv, ew, evec, sndp, rcvp, edata);

  // ---- node pre (1 launch) ----
  k_node_pre<<<5000 + cdiv_i((long long)NN * 3 * 64, 256), 256, 0, stream>>>(
      x, ln_s, ln_b, vec, xn_b, vec_b);

  // qkv = xn @ [Wq|Wk|Wv] + b  (bf16 out)
  { dim3 g(640 / 128, cdiv_i(NN, 128));
    k_gemm<128, true, false><<<g, 256, 0, stream>>>(xn_b, WTqkv, Bqkv, qkv_b, NN, 640); }
  k_headln<<<cdiv_i((long long)NN * 16, 256), 256, 0, stream>>>(qkv_b, qln_s, qln_b, kln_s, kln_b, qk_b);

  // vp = vec @ Wvec (bf16 out)
  { dim3 g(384 / 128, cdiv_i((long long)NN * 3, 128));
    k_gemm<128, true, false><<<g, 256, 0, stream>>>(vec_b, WTvec, nullptr, vp, NN * 3, 384); }

  // ---- fully fused edge phase (one launch, no intermediates) ----
  k_edge_all<<<NE / 64, 256, 0, stream>>>(ea, perm, sndp, rcvp, off, edata, WTdkv, Bdkv,
                                          qk_b, qkv_b, vec_b, xagg, vecagg);

  // o = x_agg @ Wo + bo
  k_cast_bf16<<<cdiv_i((long long)NN * 64, 256), 256, 0, stream>>>(xagg, xagg_b, NN * 64);
  { dim3 g(384 / 128, cdiv_i(NN, 128));
    k_gemm<128, false, false><<<g, 256, 0, stream>>>(xagg_b, WTo, bo, o, NN, 384); }

  // outputs
  k_final<<<cdiv_i((long long)NN * 128, 256), 256, 0, stream>>>(o, vp, xagg, vecagg);
}

// Round 8
// 361.925 us; speedup vs baseline: 2.7235x; 1.0215x over previous
//
#include <hip/hip_runtime.h>
#include <stdint.h>

#define NN 20000
#define NE 200000   // == 3125 * 64 exactly (k_edge_all assumes this)
// H=128, NH=8, HD=16, RBF=64

typedef __attribute__((ext_vector_type(8))) short bf16x8;
typedef __attribute__((ext_vector_type(4))) float f32x4;

__device__ __forceinline__ float bf2f(uint32_t u) {
  union { uint32_t i; float f; } v; v.i = u << 16; return v.f;
}
__device__ __forceinline__ uint16_t f2bf(float f) {
  union { float f; uint32_t i; } v; v.f = f;
  return (uint16_t)((v.i + 0x7fffu + ((v.i >> 16) & 1u)) >> 16);
}
__device__ __forceinline__ uint32_t pk2(float lo, float hi) {
  return (uint32_t)f2bf(lo) | ((uint32_t)f2bf(hi) << 16);
}
__device__ __forceinline__ float siluf(float x) { return x / (1.f + __expf(-x)); }
__device__ __forceinline__ float prod2(uint32_t q2, uint32_t k2, uint32_t d2) {
  return bf2f(q2 & 0xffffu) * bf2f(k2 & 0xffffu) * bf2f(d2 & 0xffffu)
       + bf2f(q2 >> 16) * bf2f(k2 >> 16) * bf2f(d2 >> 16);
}

// ---------------- consolidated weight prep (one launch) ----------------
// WTdkv2 is COLUMN-REORDERED: rows 0-127 = dk (h*16+d), 128-255 = dv part0 (xm),
// 256-383 = dv part1 (m1), 384-511 = dv part2 (m2). Bdkv2 reordered to match.
__global__ void k_prep(const float* __restrict__ Wq, const float* __restrict__ Wk,
                       const float* __restrict__ Wv, const float* __restrict__ Wvec,
                       const float* __restrict__ Wdk, const float* __restrict__ Wdv,
                       const float* __restrict__ Wo, const float* __restrict__ bq,
                       const float* __restrict__ bk, const float* __restrict__ bv,
                       const float* __restrict__ bdk, const float* __restrict__ bdv,
                       uint16_t* __restrict__ WTqkv, uint16_t* __restrict__ WTvec,
                       uint16_t* __restrict__ WTdkv2, uint16_t* __restrict__ WTo,
                       float* __restrict__ Bqkv, float* __restrict__ Bdkv2) {
  int idx = blockIdx.x * 256 + threadIdx.x;
  if (idx < 81920) {                       // WTqkv [640][128]
    int j = idx;
    float v;
    if (j < 16384)      { int c = j >> 7, k = j & 127; v = Wq[k * 128 + c]; }
    else if (j < 32768) { j -= 16384; int c = j >> 7, k = j & 127; v = Wk[k * 128 + c]; }
    else                { j -= 32768; int c = j >> 7, k = j & 127; v = Wv[k * 384 + c]; }
    WTqkv[idx] = f2bf(v);
    return;
  }
  idx -= 81920;
  if (idx < 49152) {                       // WTvec [384][128]
    int c = idx >> 7, k = idx & 127;
    WTvec[idx] = f2bf(Wvec[k * 384 + c]);
    return;
  }
  idx -= 49152;
  if (idx < 32768) {                       // WTdkv2 [512][64], reordered
    int rr = idx >> 6, k = idx & 63;
    float v;
    if (rr < 128) v = Wdk[k * 128 + rr];
    else {
      int j = rr - 128, p = j >> 7, hd = j & 127;
      int c = (hd >> 4) * 48 + p * 16 + (hd & 15);
      v = Wdv[k * 384 + c];
    }
    WTdkv2[idx] = f2bf(v);
    return;
  }
  idx -= 32768;
  if (idx < 49152) {                       // WTo [384][128]
    int c = idx >> 7, k = idx & 127;
    WTo[idx] = f2bf(Wo[k * 384 + c]);
    return;
  }
  idx -= 49152;
  if (idx < 640) Bqkv[idx] = (idx < 128) ? bq[idx] : ((idx < 256) ? bk[idx - 128] : bv[idx - 256]);
  else if (idx < 1152) {
    int t = idx - 640;
    if (t < 128) Bdkv2[t] = bdk[t];
    else {
      int j = t - 128, p = j >> 7, hd = j & 127;
      Bdkv2[t] = bdv[(hd >> 4) * 48 + p * 16 + (hd & 15)];
    }
  }
}

// ---------------- node pre: LN(x)->bf16  +  cast vec->bf16 (one launch) ----------------
__global__ void k_node_pre(const float* __restrict__ x, const float* __restrict__ s,
                           const float* __restrict__ b, const float* __restrict__ vec,
                           uint16_t* __restrict__ xn_b, uint16_t* __restrict__ vec_b) {
  if (blockIdx.x < 5000) {
    int gt = blockIdx.x * 256 + threadIdx.x;
    int node = gt >> 6, lane = gt & 63;
    if (node >= NN) return;
    const float* row = x + (size_t)node * 128;
    float2 v = *(const float2*)&row[lane * 2];
    float sum = v.x + v.y, sq = v.x * v.x + v.y * v.y;
    #pragma unroll
    for (int off = 32; off; off >>= 1) { sum += __shfl_xor(sum, off); sq += __shfl_xor(sq, off); }
    float mu = sum * (1.f / 128.f);
    float var = sq * (1.f / 128.f) - mu * mu;
    float rs = rsqrtf(var + 1e-6f);
    float o0 = (v.x - mu) * rs * s[lane * 2] + b[lane * 2];
    float o1 = (v.y - mu) * rs * s[lane * 2 + 1] + b[lane * 2 + 1];
    ((uint32_t*)xn_b)[(size_t)node * 64 + lane] = pk2(o0, o1);
  } else {
    int i = (blockIdx.x - 5000) * 256 + threadIdx.x;
    if (i >= NN * 3 * 64) return;
    float2 v = ((const float2*)vec)[i];
    ((uint32_t*)vec_b)[i] = pk2(v.x, v.y);
  }
}

__global__ void k_cast_bf16(const float* __restrict__ src, uint16_t* __restrict__ dst, int npairs) {
  int i = blockIdx.x * 256 + threadIdx.x;
  if (i >= npairs) return;
  float2 v = ((const float2*)src)[i];
  ((uint32_t*)dst)[i] = pk2(v.x, v.y);
}

// ---------------- edge sort by receiver (counting sort, parallel scan) ----------------
__global__ void k_hist(const int* __restrict__ rcv, int* __restrict__ deg) {
  int e = blockIdx.x * 256 + threadIdx.x;
  if (e < NE) atomicAdd(&deg[rcv[e]], 1);
}

__global__ void k_scan1(const int* __restrict__ deg, int* __restrict__ bsum) {
  __shared__ int ws[4];
  int i = blockIdx.x * 256 + threadIdx.x;
  int x = (i < NN) ? deg[i] : 0;
  #pragma unroll
  for (int d = 32; d; d >>= 1) x += __shfl_xor(x, d);
  if ((threadIdx.x & 63) == 0) ws[threadIdx.x >> 6] = x;
  __syncthreads();
  if (threadIdx.x == 0) bsum[blockIdx.x] = ws[0] + ws[1] + ws[2] + ws[3];
}

__global__ void k_scan2(int* __restrict__ bsum, int nb, int* __restrict__ off) {
  int lane = threadIdx.x;
  int carry = 0;
  for (int base = 0; base < nb; base += 64) {
    int i = base + lane;
    int x = (i < nb) ? bsum[i] : 0;
    int v = x;
    #pragma unroll
    for (int d = 1; d < 64; d <<= 1) { int y = __shfl_up(v, d); if (lane >= d) v += y; }
    if (i < nb) bsum[i] = carry + v - x;
    carry += __shfl(v, 63);
  }
  if (lane == 0) off[NN] = carry;
}

__global__ void k_scan3(const int* __restrict__ deg, const int* __restrict__ bsum,
                        int* __restrict__ off, int* __restrict__ cur) {
  __shared__ int ws[4];
  int t = threadIdx.x, lane = t & 63, w = t >> 6;
  int i = blockIdx.x * 256 + t;
  int x = (i < NN) ? deg[i] : 0;
  int v = x;
  #pragma unroll
  for (int d = 1; d < 64; d <<= 1) { int y = __shfl_up(v, d); if (lane >= d) v += y; }
  if (lane == 63) ws[w] = v;
  __syncthreads();
  int wadd = 0;
  for (int j = 0; j < w; j++) wadd += ws[j];
  int excl = bsum[blockIdx.x] + wadd + v - x;
  if (i < NN) { off[i] = excl; cur[i] = excl; }
}

__global__ void k_scatter(const int* __restrict__ rcv, int* __restrict__ cur,
                          int* __restrict__ perm) {
  int e = blockIdx.x * 256 + threadIdx.x;
  if (e >= NE) return;
  int pos = atomicAdd(&cur[rcv[e]], 1);
  perm[pos] = e;
}

// gather+cast edge_attr rows in permuted order; also permute snd/rcv and
// pack (evec.xyz, cutoff(ew)) into edata
__global__ void k_permute(const float* __restrict__ ea, const int* __restrict__ perm,
                          const int* __restrict__ snd, const int* __restrict__ rcv,
                          const float* __restrict__ ew, const float* __restrict__ evec,
                          uint16_t* __restrict__ ea_perm, int* __restrict__ sndp,
                          int* __restrict__ rcvp, float4* __restrict__ edata) {
  int idx = blockIdx.x * 256 + threadIdx.x;   // 16 threads per edge
  if (idx >= NE * 16) return;
  int i = idx >> 4, j = idx & 15;
  int e = perm[i];
  float4 v = *(const float4*)&ea[(size_t)e * 64 + j * 4];
  uint2 o;
  o.x = pk2(v.x, v.y);
  o.y = pk2(v.z, v.w);
  *(uint2*)&ea_perm[(size_t)i * 64 + j * 4] = o;
  if (j == 0) {
    sndp[i] = snd[e];
    rcvp[i] = rcv[e];
    float w = ew[e];
    float cut = (w < 5.f) ? 0.5f * (__cosf(w * 0.628318530717958648f) + 1.f) : 0.f;
    edata[i] = make_float4(evec[e * 3], evec[e * 3 + 1], evec[e * 3 + 2], cut);
  }
}

// ---------------- bf16 MFMA GEMM: C = act(A @ BT^T + bias) ----------------
template <int KTOT, bool OUT_BF16, bool SILU>
__global__ __launch_bounds__(256) void k_gemm(const uint16_t* __restrict__ A,
                                              const uint16_t* __restrict__ BT,
                                              const float* __restrict__ bias,
                                              void* __restrict__ Cout, int M, int Fo) {
  __shared__ __align__(16) uint16_t As[128 * 72];
  __shared__ __align__(16) uint16_t Bs[128 * 72];
  int t = threadIdx.x;
  int l = t & 63;
  int row0 = blockIdx.y * 128, col0 = blockIdx.x * 128;
  int wm = ((t >> 6) >> 1) * 64, wn = ((t >> 6) & 1) * 64;
  f32x4 acc[4][4] = {};
  for (int kt = 0; kt < KTOT; kt += 64) {
    __syncthreads();
    #pragma unroll
    for (int i = 0; i < 4; i++) {
      int c = i * 256 + t;
      int row = c >> 3, ko = (c & 7) * 8;
      uint4 av = make_uint4(0u, 0u, 0u, 0u);
      int gr = row0 + row;
      if (gr < M) av = *(const uint4*)&A[(size_t)gr * KTOT + kt + ko];
      *(uint4*)&As[row * 72 + ko] = av;
      uint4 bw = *(const uint4*)&BT[(size_t)(col0 + row) * KTOT + kt + ko];
      *(uint4*)&Bs[row * 72 + ko] = bw;
    }
    __syncthreads();
    #pragma unroll
    for (int kk = 0; kk < 64; kk += 32) {
      bf16x8 af[4], bfr[4];
      #pragma unroll
      for (int mf = 0; mf < 4; mf++)
        af[mf] = *(const bf16x8*)&As[(wm + mf * 16 + (l & 15)) * 72 + (l >> 4) * 8 + kk];
      #pragma unroll
      for (int nf = 0; nf < 4; nf++)
        bfr[nf] = *(const bf16x8*)&Bs[(wn + nf * 16 + (l & 15)) * 72 + (l >> 4) * 8 + kk];
      #pragma unroll
      for (int mf = 0; mf < 4; mf++)
        #pragma unroll
        for (int nf = 0; nf < 4; nf++)
          acc[mf][nf] = __builtin_amdgcn_mfma_f32_16x16x32_bf16(af[mf], bfr[nf], acc[mf][nf], 0, 0, 0);
    }
  }
  float* Cf = (float*)Cout;
  uint16_t* Cb = (uint16_t*)Cout;
  #pragma unroll
  for (int mf = 0; mf < 4; mf++) {
    #pragma unroll
    for (int r = 0; r < 4; r++) {
      int grow = row0 + wm + mf * 16 + (l >> 4) * 4 + r;
      if (grow >= M) continue;
      #pragma unroll
      for (int nf = 0; nf < 4; nf++) {
        int gcol = col0 + wn + nf * 16 + (l & 15);
        float v = acc[mf][nf][r];
        if (bias) v += bias[gcol];
        if (SILU) v = siluf(v);
        if (OUT_BF16) Cb[(size_t)grow * Fo + gcol] = f2bf(v);
        else          Cf[(size_t)grow * Fo + gcol] = v;
      }
    }
  }
}

// ---------------- per-head LN on q/k (bf16 in/out) ----------------
__global__ void k_headln(const uint16_t* __restrict__ qkv, const float* __restrict__ qs,
                         const float* __restrict__ qb, const float* __restrict__ ks,
                         const float* __restrict__ kb, uint16_t* __restrict__ out) {
  int idx = blockIdx.x * 256 + threadIdx.x;
  if (idx >= NN * 16) return;
  int n = idx >> 4, ph = idx & 15, part = ph >> 3, h = ph & 7;
  const uint16_t* src = qkv + (size_t)n * 640 + part * 128 + h * 16;
  float v[16], sum = 0.f;
  #pragma unroll
  for (int i = 0; i < 16; i++) { v[i] = bf2f(src[i]); sum += v[i]; }
  float mu = sum * (1.f / 16.f), var = 0.f;
  #pragma unroll
  for (int i = 0; i < 16; i++) { float dd = v[i] - mu; var += dd * dd; }
  float rs = rsqrtf(var * (1.f / 16.f) + 1e-6f);
  const float* sc = part ? ks : qs;
  const float* bb = part ? kb : qb;
  uint16_t* dst = out + (size_t)n * 256 + part * 128 + h * 16;
  #pragma unroll
  for (int i = 0; i < 16; i++) dst[i] = f2bf((v[i] - mu) * rs * sc[i] + bb[i]);
}

// ---------------- FULLY FUSED edge phase (32-edge halves, 5 blocks/CU) ----------------
__device__ __forceinline__ void mfma32(const uint16_t* As, int r0,
                                       const uint16_t* __restrict__ BT2, int cb,
                                       int wn, int l, f32x4 acc[2][2]) {
  #pragma unroll
  for (int kk = 0; kk < 2; kk++) {
    bf16x8 af[2];
    #pragma unroll
    for (int mf = 0; mf < 2; mf++)
      af[mf] = *(const bf16x8*)&As[(r0 + mf * 16 + (l & 15)) * 68 + (l >> 4) * 8 + kk * 32];
    #pragma unroll
    for (int nf = 0; nf < 2; nf++) {
      bf16x8 bv = *(const bf16x8*)&BT2[(size_t)(cb * 128 + wn + nf * 16 + (l & 15)) * 64 +
                                       (l >> 4) * 8 + kk * 32];
      #pragma unroll
      for (int mf = 0; mf < 2; mf++)
        acc[mf][nf] = __builtin_amdgcn_mfma_f32_16x16x32_bf16(af[mf], bv, acc[mf][nf], 0, 0, 0);
    }
  }
}

__device__ __forceinline__ void silu_store32(uint16_t* mt, const float* bsv,
                                             int wn, int l, f32x4 acc[2][2]) {
  #pragma unroll
  for (int mf = 0; mf < 2; mf++)
    #pragma unroll
    for (int r = 0; r < 4; r++) {
      int row = mf * 16 + (l >> 4) * 4 + r;
      #pragma unroll
      for (int nf = 0; nf < 2; nf++) {
        int c = wn + nf * 16 + (l & 15);
        mt[row * 140 + c] = f2bf(siluf(acc[mf][nf][r] + bsv[nf]));
      }
    }
}

__global__ __launch_bounds__(256) void k_edge_all(
    const uint16_t* __restrict__ eap, const int* __restrict__ sndp,
    const int* __restrict__ rcvp, const int* __restrict__ off,
    const float4* __restrict__ edata, const uint16_t* __restrict__ WT2,
    const float* __restrict__ Bd2, const uint16_t* __restrict__ qk_b,
    const uint16_t* __restrict__ qkv_b, const uint16_t* __restrict__ vec_b,
    float* __restrict__ xagg, float* __restrict__ vecagg) {
  __shared__ __align__(16) uint16_t As[64 * 68];     // 8.7 KB
  __shared__ __align__(16) uint16_t mtA[32 * 140];   // 8.96 KB
  __shared__ __align__(16) uint16_t mtB[32 * 140];   // 8.96 KB
  __shared__ float attn_l[32 * 8];                   // 1 KB
  __shared__ int sndl[64], rcvl[64], lo_g[64], hi_g[64];
  __shared__ float4 ed4[64];

  int e0 = blockIdx.x * 64;
  int t = threadIdx.x, l = t & 63, wn = (t >> 6) * 32;

  // ---- meta + A stage + bias regs ----
  if (t < 64) {
    int e = e0 + t;
    int r = rcvp[e];
    sndl[t] = sndp[e]; rcvl[t] = r;
    lo_g[t] = off[r]; hi_g[t] = off[r + 1];
    ed4[t] = edata[e];
  }
  #pragma unroll
  for (int i = 0; i < 2; i++) {
    int c = i * 256 + t;
    int row = c >> 3, ko = (c & 7) * 8;
    *(uint4*)&As[row * 68 + ko] = *(const uint4*)&eap[(size_t)(e0 + row) * 64 + ko];
  }
  float bs[4][2];
  #pragma unroll
  for (int cb = 0; cb < 4; cb++) {
    bs[cb][0] = Bd2[cb * 128 + wn + (l & 15)];
    bs[cb][1] = Bd2[cb * 128 + wn + 16 + (l & 15)];
  }
  __syncthreads();

  #pragma unroll
  for (int half = 0; half < 2; half++) {
    int r0 = half * 32;
    // cb0: dk -> mtA
    { f32x4 acc[2][2] = {}; mfma32(As, r0, WT2, 0, wn, l, acc); silu_store32(mtA, bs[0], wn, l, acc); }
    __syncthreads();
    // attn: exactly 256 tasks = 32 edges x 8 heads
    {
      int el = t >> 3, h = t & 7;
      int ge = r0 + el;
      int rn = rcvl[ge], sn = sndl[ge];
      const uint32_t* qp = (const uint32_t*)(qk_b + (size_t)rn * 256 + h * 16);
      const uint32_t* kp = (const uint32_t*)(qk_b + (size_t)sn * 256 + 128 + h * 16);
      const uint32_t* dp = (const uint32_t*)&mtA[el * 140 + h * 16];
      float dot = 0.f;
      #pragma unroll
      for (int j = 0; j < 8; j++) dot += prod2(qp[j], kp[j], dp[j]);
      attn_l[el * 8 + h] = siluf(dot) * ed4[ge].w;
    }
    __syncthreads();
    // cb1: xm -> mtA
    { f32x4 acc[2][2] = {}; mfma32(As, r0, WT2, 1, wn, l, acc); silu_store32(mtA, bs[1], wn, l, acc); }
    __syncthreads();
    // xm walk: thread = (col, 16-edge sub-window)
    {
      int col = t & 127, sub = t >> 7;
      int i0 = r0 + sub * 16, i1 = i0 + 16;
      int voff = 256 + (col >> 4) * 48 + (col & 15);
      float accx = 0.f;
      #pragma unroll 8
      for (int i = i0; i < i1; i++) {
        int n = rcvl[i];
        float m = bf2f(mtA[(i - r0) * 140 + col]);
        float a = attn_l[(i - r0) * 8 + (col >> 4)];
        float v0 = bf2f(qkv_b[(size_t)sndl[i] * 640 + voff]);
        accx += v0 * m * a;
        if (i == i1 - 1 || rcvl[i + 1] != n) {
          float* dst = &xagg[(size_t)n * 128 + col];
          if (lo_g[i] >= e0 + i0 && hi_g[i] <= e0 + i1) *dst = accx;
          else atomicAdd(dst, accx);
          accx = 0.f;
        }
      }
    }
    __syncthreads();
    // cb2: m1 -> mtA ; cb3: m2 -> mtB
    { f32x4 acc[2][2] = {}; mfma32(As, r0, WT2, 2, wn, l, acc); silu_store32(mtA, bs[2], wn, l, acc); }
    { f32x4 acc[2][2] = {}; mfma32(As, r0, WT2, 3, wn, l, acc); silu_store32(mtB, bs[3], wn, l, acc); }
    __syncthreads();
    // m walk
    {
      int col = t & 127, sub = t >> 7;
      int i0 = r0 + sub * 16, i1 = i0 + 16;
      int v1o = 256 + (col >> 4) * 48 + 16 + (col & 15);
      float a0 = 0.f, a1 = 0.f, a2 = 0.f;
      #pragma unroll 8
      for (int i = i0; i < i1; i++) {
        int n = rcvl[i];
        int s = sndl[i];
        float m1d = bf2f(mtA[(i - r0) * 140 + col]);
        float m2d = bf2f(mtB[(i - r0) * 140 + col]);
        const uint16_t* vb = qkv_b + (size_t)s * 640 + v1o;
        float mm1 = bf2f(vb[0]) * m1d;
        float mm2 = bf2f(vb[16]) * m2d;
        const uint16_t* vv = vec_b + (size_t)s * 384 + col;
        float4 ev = ed4[i];
        a0 += bf2f(vv[0])   * mm1 + ev.x * mm2;
        a1 += bf2f(vv[128]) * mm1 + ev.y * mm2;
        a2 += bf2f(vv[256]) * mm1 + ev.z * mm2;
        if (i == i1 - 1 || rcvl[i + 1] != n) {
          float* d0 = &vecagg[((size_t)n * 3 + 0) * 128 + col];
          float* d1 = &vecagg[((size_t)n * 3 + 1) * 128 + col];
          float* d2 = &vecagg[((size_t)n * 3 + 2) * 128 + col];
          if (lo_g[i] >= e0 + i0 && hi_g[i] <= e0 + i1) { *d0 = a0; *d1 = a1; *d2 = a2; }
          else { atomicAdd(d0, a0); atomicAdd(d1, a1); atomicAdd(d2, a2); }
          a0 = a1 = a2 = 0.f;
        }
      }
    }
    __syncthreads();
  }
}

// ---------------- final ----------------
__global__ void k_final(const float* __restrict__ o, const uint16_t* __restrict__ vp,
                        float* __restrict__ dx, float* __restrict__ dvec) {
  int idx = blockIdx.x * 256 + threadIdx.x;
  if (idx >= NN * 128) return;
  int n = idx >> 7, j = idx & 127;
  const float* op = o + (size_t)n * 384;
  float o1 = op[j], o2 = op[128 + j], o3 = op[256 + j];
  const uint16_t* vpn = vp + (size_t)n * 3 * 384;
  float vd = 0.f;
  #pragma unroll
  for (int c = 0; c < 3; c++)
    vd += bf2f(vpn[c * 384 + j]) * bf2f(vpn[c * 384 + 128 + j]);
  dx[idx] = vd * o2 + o3;
  #pragma unroll
  for (int c = 0; c < 3; c++) {
    size_t vi = ((size_t)n * 3 + c) * 128 + j;
    dvec[vi] = bf2f(vpn[c * 384 + 256 + j]) * o1 + dvec[vi];
  }
}

static inline int cdiv_i(long long a, long long b) { return (int)((a + b - 1) / b); }

extern "C" void kernel_launch(void* const* d_in, const int* in_sizes, int n_in,
                              void* d_out, int out_size, void* d_ws, size_t ws_size,
                              hipStream_t stream) {
  const float* x    = (const float*)d_in[0];
  const float* vec  = (const float*)d_in[1];
  const float* ew   = (const float*)d_in[2];
  const float* ea   = (const float*)d_in[3];
  const float* evec = (const float*)d_in[4];
  const int*   snd  = (const int*)d_in[5];
  const int*   rcv  = (const int*)d_in[6];
  const float* ln_s = (const float*)d_in[7];
  const float* ln_b = (const float*)d_in[8];
  const float* Wq = (const float*)d_in[9];   const float* bq = (const float*)d_in[10];
  const float* Wk = (const float*)d_in[11];  const float* bk = (const float*)d_in[12];
  const float* Wv = (const float*)d_in[13];  const float* bv = (const float*)d_in[14];
  const float* Wvec = (const float*)d_in[15];
  const float* Wdk = (const float*)d_in[16]; const float* bdk = (const float*)d_in[17];
  const float* Wdv = (const float*)d_in[18]; const float* bdv = (const float*)d_in[19];
  const float* Wo = (const float*)d_in[20];  const float* bo = (const float*)d_in[21];
  const float* qln_s = (const float*)d_in[22]; const float* qln_b = (const float*)d_in[23];
  const float* kln_s = (const float*)d_in[24]; const float* kln_b = (const float*)d_in[25];
  (void)in_sizes; (void)n_in; (void)ws_size;

  uint8_t* p = (uint8_t*)d_ws;
  auto alloc = [&](size_t bytes) -> uint8_t* {
    uint8_t* r = p; p += (bytes + 255) & ~(size_t)255; return r;
  };
  uint16_t* WTqkv = (uint16_t*)alloc(640 * 128 * 2);
  float*    Bqkv  = (float*)alloc(640 * 4);
  uint16_t* WTvec = (uint16_t*)alloc(384 * 128 * 2);
  uint16_t* WTdkv = (uint16_t*)alloc(512 * 64 * 2);
  float*    Bdkv  = (float*)alloc(512 * 4);
  uint16_t* WTo   = (uint16_t*)alloc(384 * 128 * 2);
  int*      deg   = (int*)alloc(NN * 4);
  int*      off   = (int*)alloc((NN + 1) * 4);
  int*      cur   = (int*)alloc(NN * 4);
  int*      bsum  = (int*)alloc(256 * 4);
  int*      perm  = (int*)alloc((size_t)NE * 4);
  int*      sndp  = (int*)alloc((size_t)NE * 4);
  int*      rcvp  = (int*)alloc((size_t)NE * 4);
  float4*   edata = (float4*)alloc((size_t)NE * 16);
  uint16_t* ea_perm = (uint16_t*)alloc((size_t)NE * 64 * 2);
  uint16_t* xn_b  = (uint16_t*)alloc((size_t)NN * 128 * 2);
  uint16_t* qkv_b = (uint16_t*)alloc((size_t)NN * 640 * 2);
  uint16_t* qk_b  = (uint16_t*)alloc((size_t)NN * 256 * 2);
  uint16_t* vec_b = (uint16_t*)alloc((size_t)NN * 3 * 128 * 2);
  uint16_t* vp    = (uint16_t*)alloc((size_t)NN * 3 * 384 * 2);
  float*    o      = (float*)alloc((size_t)NN * 384 * 4);
  uint16_t* xagg_b = (uint16_t*)alloc((size_t)NN * 128 * 2);

  float* xagg   = (float*)d_out;
  float* vecagg = (float*)d_out + (size_t)NN * 128;

  hipMemsetAsync(d_out, 0, (size_t)out_size * 4, stream);

  // ---- weights prep (1 launch) ----
  k_prep<<<cdiv_i(81920 + 49152 + 32768 + 49152 + 1152, 256), 256, 0, stream>>>(
      Wq, Wk, Wv, Wvec, Wdk, Wdv, Wo, bq, bk, bv, bdk, bdv,
      WTqkv, WTvec, WTdkv, WTo, Bqkv, Bdkv);

  // ---- edge sort by receiver ----
  int NSB = cdiv_i(NN, 256);
  hipMemsetAsync(deg, 0, NN * 4, stream);
  k_hist<<<cdiv_i(NE, 256), 256, 0, stream>>>(rcv, deg);
  k_scan1<<<NSB, 256, 0, stream>>>(deg, bsum);
  k_scan2<<<1, 64, 0, stream>>>(bsum, NSB, off);
  k_scan3<<<NSB, 256, 0, stream>>>(deg, bsum, off, cur);
  k_scatter<<<cdiv_i(NE, 256), 256, 0, stream>>>(rcv, cur, perm);
  k_permute<<<cdiv_i((long long)NE * 16, 256), 256, 0, stream>>>(ea, perm, snd, rcv, ew, evec,
                                                                 ea_perm, sndp, rcvp, edata);

  // ---- node pre (1 launch) ----
  k_node_pre<<<5000 + cdiv_i((long long)NN * 3 * 64, 256), 256, 0, stream>>>(
      x, ln_s, ln_b, vec, xn_b, vec_b);

  // qkv = xn @ [Wq|Wk|Wv] + b  (bf16 out)
  { dim3 g(640 / 128, cdiv_i(NN, 128));
    k_gemm<128, true, false><<<g, 256, 0, stream>>>(xn_b, WTqkv, Bqkv, qkv_b, NN, 640); }
  k_headln<<<cdiv_i((long long)NN * 16, 256), 256, 0, stream>>>(qkv_b, qln_s, qln_b, kln_s, kln_b, qk_b);

  // vp = vec @ Wvec (bf16 out)
  { dim3 g(384 / 128, cdiv_i((long long)NN * 3, 128));
    k_gemm<128, true, false><<<g, 256, 0, stream>>>(vec_b, WTvec, nullptr, vp, NN * 3, 384); }

  // ---- fully fused edge phase (one launch, no intermediates) ----
  k_edge_all<<<NE / 64, 256, 0, stream>>>(ea_perm, sndp, rcvp, off, edata, WTdkv, Bdkv,
                                          qk_b, qkv_b, vec_b, xagg, vecagg);

  // o = x_agg @ Wo + bo
  k_cast_bf16<<<cdiv_i((long long)NN * 64, 256), 256, 0, stream>>>(xagg, xagg_b, NN * 64);
  { dim3 g(384 / 128, cdiv_i(NN, 128));
    k_gemm<128, false, false><<<g, 256, 0, stream>>>(xagg_b, WTo, bo, o, NN, 384); }

  // outputs
  k_final<<<cdiv_i((long long)NN * 128, 256), 256, 0, stream>>>(o, vp, xagg, vecagg);
}

// Round 9
// 347.942 us; speedup vs baseline: 2.8330x; 1.0402x over previous
//
#include <hip/hip_runtime.h>
#include <stdint.h>

#define NN 20000
#define NE 200000   // == 3125 * 64 exactly (k_edge_all assumes this)
// H=128, NH=8, HD=16, RBF=64

typedef __attribute__((ext_vector_type(8))) short bf16x8;
typedef __attribute__((ext_vector_type(4))) float f32x4;

__device__ __forceinline__ float bf2f(uint32_t u) {
  union { uint32_t i; float f; } v; v.i = u << 16; return v.f;
}
__device__ __forceinline__ uint16_t f2bf(float f) {
  union { float f; uint32_t i; } v; v.f = f;
  return (uint16_t)((v.i + 0x7fffu + ((v.i >> 16) & 1u)) >> 16);
}
__device__ __forceinline__ uint32_t pk2(float lo, float hi) {
  return (uint32_t)f2bf(lo) | ((uint32_t)f2bf(hi) << 16);
}
__device__ __forceinline__ float siluf(float x) { return x / (1.f + __expf(-x)); }

// ---------------- consolidated weight prep (one launch) ----------------
// WTqkv [768][128]: rows 0-255 = q|k as before; rows 256-767 = v-part
// INTERLEAVED: row 256 + j*4 + c  (j = h*16+d, c=0..2 from orig col h*48+c*16+d,
// c==3 is a zero pad column). WTdkv2 column-reordered as in R7/R8.
__global__ void k_prep(const float* __restrict__ Wq, const float* __restrict__ Wk,
                       const float* __restrict__ Wv, const float* __restrict__ Wvec,
                       const float* __restrict__ Wdk, const float* __restrict__ Wdv,
                       const float* __restrict__ Wo, const float* __restrict__ bq,
                       const float* __restrict__ bk, const float* __restrict__ bv,
                       const float* __restrict__ bdk, const float* __restrict__ bdv,
                       uint16_t* __restrict__ WTqkv, uint16_t* __restrict__ WTvec,
                       uint16_t* __restrict__ WTdkv2, uint16_t* __restrict__ WTo,
                       float* __restrict__ Bqkv, float* __restrict__ Bdkv2) {
  int idx = blockIdx.x * 256 + threadIdx.x;
  if (idx < 98304) {                       // WTqkv [768][128]
    int rr = idx >> 7, k = idx & 127;
    float v;
    if (rr < 128)      v = Wq[k * 128 + rr];
    else if (rr < 256) v = Wk[k * 128 + rr - 128];
    else {
      int j2 = rr - 256, j = j2 >> 2, c = j2 & 3;
      v = (c < 3) ? Wv[k * 384 + (j >> 4) * 48 + c * 16 + (j & 15)] : 0.f;
    }
    WTqkv[idx] = f2bf(v);
    return;
  }
  idx -= 98304;
  if (idx < 49152) {                       // WTvec [384][128]
    int c = idx >> 7, k = idx & 127;
    WTvec[idx] = f2bf(Wvec[k * 384 + c]);
    return;
  }
  idx -= 49152;
  if (idx < 32768) {                       // WTdkv2 [512][64], reordered
    int rr = idx >> 6, k = idx & 63;
    float v;
    if (rr < 128) v = Wdk[k * 128 + rr];
    else {
      int j = rr - 128, p = j >> 7, hd = j & 127;
      v = Wdv[k * 384 + (hd >> 4) * 48 + p * 16 + (hd & 15)];
    }
    WTdkv2[idx] = f2bf(v);
    return;
  }
  idx -= 32768;
  if (idx < 49152) {                       // WTo [384][128]
    int c = idx >> 7, k = idx & 127;
    WTo[idx] = f2bf(Wo[k * 384 + c]);
    return;
  }
  idx -= 49152;
  if (idx < 768) {                         // Bqkv [768]
    if (idx < 128)      Bqkv[idx] = bq[idx];
    else if (idx < 256) Bqkv[idx] = bk[idx - 128];
    else {
      int j2 = idx - 256, j = j2 >> 2, c = j2 & 3;
      Bqkv[idx] = (c < 3) ? bv[(j >> 4) * 48 + c * 16 + (j & 15)] : 0.f;
    }
  } else if (idx < 1280) {
    int t = idx - 768;
    if (t < 128) Bdkv2[t] = bdk[t];
    else {
      int j = t - 128, p = j >> 7, hd = j & 127;
      Bdkv2[t] = bdv[(hd >> 4) * 48 + p * 16 + (hd & 15)];
    }
  }
}

// ---------------- node pre: LN(x)->bf16 + vec GEMM-layout + vec walk-layout ----------------
__global__ void k_node_pre(const float* __restrict__ x, const float* __restrict__ s,
                           const float* __restrict__ b, const float* __restrict__ vec,
                           uint16_t* __restrict__ xn_b, uint16_t* __restrict__ vec_b,
                           uint16_t* __restrict__ vec_w) {
  if (blockIdx.x < 5000) {
    int gt = blockIdx.x * 256 + threadIdx.x;
    int node = gt >> 6, lane = gt & 63;
    if (node >= NN) return;
    const float* row = x + (size_t)node * 128;
    float2 v = *(const float2*)&row[lane * 2];
    float sum = v.x + v.y, sq = v.x * v.x + v.y * v.y;
    #pragma unroll
    for (int off = 32; off; off >>= 1) { sum += __shfl_xor(sum, off); sq += __shfl_xor(sq, off); }
    float mu = sum * (1.f / 128.f);
    float var = sq * (1.f / 128.f) - mu * mu;
    float rs = rsqrtf(var + 1e-6f);
    float o0 = (v.x - mu) * rs * s[lane * 2] + b[lane * 2];
    float o1 = (v.y - mu) * rs * s[lane * 2 + 1] + b[lane * 2 + 1];
    ((uint32_t*)xn_b)[(size_t)node * 64 + lane] = pk2(o0, o1);
  } else if (blockIdx.x < 20000) {
    int i = (blockIdx.x - 5000) * 256 + threadIdx.x;   // NN*3*64 pairs
    float2 v = ((const float2*)vec)[i];
    ((uint32_t*)vec_b)[i] = pk2(v.x, v.y);
  } else {
    int i = (blockIdx.x - 20000) * 256 + threadIdx.x;  // NN*128 triples
    int n = i >> 7, j = i & 127;
    const float* vr = vec + (size_t)n * 384 + j;
    uint2 o;
    o.x = pk2(vr[0], vr[128]);
    o.y = pk2(vr[256], 0.f);
    *(uint2*)&vec_w[(size_t)n * 512 + j * 4] = o;
  }
}

__global__ void k_cast_bf16(const float* __restrict__ src, uint16_t* __restrict__ dst, int npairs) {
  int i = blockIdx.x * 256 + threadIdx.x;
  if (i >= npairs) return;
  float2 v = ((const float2*)src)[i];
  ((uint32_t*)dst)[i] = pk2(v.x, v.y);
}

// ---------------- edge sort by receiver (counting sort, parallel scan) ----------------
__global__ void k_hist(const int* __restrict__ rcv, int* __restrict__ deg) {
  int e = blockIdx.x * 256 + threadIdx.x;
  if (e < NE) atomicAdd(&deg[rcv[e]], 1);
}

__global__ void k_scan1(const int* __restrict__ deg, int* __restrict__ bsum) {
  __shared__ int ws[4];
  int i = blockIdx.x * 256 + threadIdx.x;
  int x = (i < NN) ? deg[i] : 0;
  #pragma unroll
  for (int d = 32; d; d >>= 1) x += __shfl_xor(x, d);
  if ((threadIdx.x & 63) == 0) ws[threadIdx.x >> 6] = x;
  __syncthreads();
  if (threadIdx.x == 0) bsum[blockIdx.x] = ws[0] + ws[1] + ws[2] + ws[3];
}

__global__ void k_scan2(int* __restrict__ bsum, int nb, int* __restrict__ off) {
  int lane = threadIdx.x;
  int carry = 0;
  for (int base = 0; base < nb; base += 64) {
    int i = base + lane;
    int x = (i < nb) ? bsum[i] : 0;
    int v = x;
    #pragma unroll
    for (int d = 1; d < 64; d <<= 1) { int y = __shfl_up(v, d); if (lane >= d) v += y; }
    if (i < nb) bsum[i] = carry + v - x;
    carry += __shfl(v, 63);
  }
  if (lane == 0) off[NN] = carry;
}

__global__ void k_scan3(const int* __restrict__ deg, const int* __restrict__ bsum,
                        int* __restrict__ off, int* __restrict__ cur) {
  __shared__ int ws[4];
  int t = threadIdx.x, lane = t & 63, w = t >> 6;
  int i = blockIdx.x * 256 + t;
  int x = (i < NN) ? deg[i] : 0;
  int v = x;
  #pragma unroll
  for (int d = 1; d < 64; d <<= 1) { int y = __shfl_up(v, d); if (lane >= d) v += y; }
  if (lane == 63) ws[w] = v;
  __syncthreads();
  int wadd = 0;
  for (int j = 0; j < w; j++) wadd += ws[j];
  int excl = bsum[blockIdx.x] + wadd + v - x;
  if (i < NN) { off[i] = excl; cur[i] = excl; }
}

__global__ void k_scatter(const int* __restrict__ rcv, int* __restrict__ cur,
                          int* __restrict__ perm) {
  int e = blockIdx.x * 256 + threadIdx.x;
  if (e >= NE) return;
  int pos = atomicAdd(&cur[rcv[e]], 1);
  perm[pos] = e;
}

// gather+cast edge_attr rows in permuted order; also permute snd/rcv and
// pack (evec.xyz, cutoff(ew)) into edata
__global__ void k_permute(const float* __restrict__ ea, const int* __restrict__ perm,
                          const int* __restrict__ snd, const int* __restrict__ rcv,
                          const float* __restrict__ ew, const float* __restrict__ evec,
                          uint16_t* __restrict__ ea_perm, int* __restrict__ sndp,
                          int* __restrict__ rcvp, float4* __restrict__ edata) {
  int idx = blockIdx.x * 256 + threadIdx.x;   // 16 threads per edge
  if (idx >= NE * 16) return;
  int i = idx >> 4, j = idx & 15;
  int e = perm[i];
  float4 v = *(const float4*)&ea[(size_t)e * 64 + j * 4];
  uint2 o;
  o.x = pk2(v.x, v.y);
  o.y = pk2(v.z, v.w);
  *(uint2*)&ea_perm[(size_t)i * 64 + j * 4] = o;
  if (j == 0) {
    sndp[i] = snd[e];
    rcvp[i] = rcv[e];
    float w = ew[e];
    float cut = (w < 5.f) ? 0.5f * (__cosf(w * 0.628318530717958648f) + 1.f) : 0.f;
    edata[i] = make_float4(evec[e * 3], evec[e * 3 + 1], evec[e * 3 + 2], cut);
  }
}

// ---------------- bf16 MFMA GEMM: C = act(A @ BT^T + bias) ----------------
template <int KTOT, bool OUT_BF16, bool SILU>
__global__ __launch_bounds__(256) void k_gemm(const uint16_t* __restrict__ A,
                                              const uint16_t* __restrict__ BT,
                                              const float* __restrict__ bias,
                                              void* __restrict__ Cout, int M, int Fo) {
  __shared__ __align__(16) uint16_t As[128 * 72];
  __shared__ __align__(16) uint16_t Bs[128 * 72];
  int t = threadIdx.x;
  int l = t & 63;
  int row0 = blockIdx.y * 128, col0 = blockIdx.x * 128;
  int wm = ((t >> 6) >> 1) * 64, wn = ((t >> 6) & 1) * 64;
  f32x4 acc[4][4] = {};
  for (int kt = 0; kt < KTOT; kt += 64) {
    __syncthreads();
    #pragma unroll
    for (int i = 0; i < 4; i++) {
      int c = i * 256 + t;
      int row = c >> 3, ko = (c & 7) * 8;
      uint4 av = make_uint4(0u, 0u, 0u, 0u);
      int gr = row0 + row;
      if (gr < M) av = *(const uint4*)&A[(size_t)gr * KTOT + kt + ko];
      *(uint4*)&As[row * 72 + ko] = av;
      uint4 bw = *(const uint4*)&BT[(size_t)(col0 + row) * KTOT + kt + ko];
      *(uint4*)&Bs[row * 72 + ko] = bw;
    }
    __syncthreads();
    #pragma unroll
    for (int kk = 0; kk < 64; kk += 32) {
      bf16x8 af[4], bfr[4];
      #pragma unroll
      for (int mf = 0; mf < 4; mf++)
        af[mf] = *(const bf16x8*)&As[(wm + mf * 16 + (l & 15)) * 72 + (l >> 4) * 8 + kk];
      #pragma unroll
      for (int nf = 0; nf < 4; nf++)
        bfr[nf] = *(const bf16x8*)&Bs[(wn + nf * 16 + (l & 15)) * 72 + (l >> 4) * 8 + kk];
      #pragma unroll
      for (int mf = 0; mf < 4; mf++)
        #pragma unroll
        for (int nf = 0; nf < 4; nf++)
          acc[mf][nf] = __builtin_amdgcn_mfma_f32_16x16x32_bf16(af[mf], bfr[nf], acc[mf][nf], 0, 0, 0);
    }
  }
  float* Cf = (float*)Cout;
  uint16_t* Cb = (uint16_t*)Cout;
  #pragma unroll
  for (int mf = 0; mf < 4; mf++) {
    #pragma unroll
    for (int r = 0; r < 4; r++) {
      int grow = row0 + wm + mf * 16 + (l >> 4) * 4 + r;
      if (grow >= M) continue;
      #pragma unroll
      for (int nf = 0; nf < 4; nf++) {
        int gcol = col0 + wn + nf * 16 + (l & 15);
        float v = acc[mf][nf][r];
        if (bias) v += bias[gcol];
        if (SILU) v = siluf(v);
        if (OUT_BF16) Cb[(size_t)grow * Fo + gcol] = f2bf(v);
        else          Cf[(size_t)grow * Fo + gcol] = v;
      }
    }
  }
}

// ---------------- per-head LN on q/k (bf16 in/out, qkv row stride 768) ----------------
__global__ void k_headln(const uint16_t* __restrict__ qkv, const float* __restrict__ qs,
                         const float* __restrict__ qb, const float* __restrict__ ks,
                         const float* __restrict__ kb, uint16_t* __restrict__ out) {
  int idx = blockIdx.x * 256 + threadIdx.x;
  if (idx >= NN * 16) return;
  int n = idx >> 4, ph = idx & 15, part = ph >> 3, h = ph & 7;
  const uint16_t* src = qkv + (size_t)n * 768 + part * 128 + h * 16;
  float v[16], sum = 0.f;
  #pragma unroll
  for (int i = 0; i < 16; i++) { v[i] = bf2f(src[i]); sum += v[i]; }
  float mu = sum * (1.f / 16.f), var = 0.f;
  #pragma unroll
  for (int i = 0; i < 16; i++) { float dd = v[i] - mu; var += dd * dd; }
  float rs = rsqrtf(var * (1.f / 16.f) + 1e-6f);
  const float* sc = part ? ks : qs;
  const float* bb = part ? kb : qb;
  uint16_t* dst = out + (size_t)n * 256 + part * 128 + h * 16;
  #pragma unroll
  for (int i = 0; i < 16; i++) dst[i] = f2bf((v[i] - mu) * rs * sc[i] + bb[i]);
}

// ---------------- FULLY FUSED edge phase (5 barriers, slot-interleaved LDS) ----------------
#define MTS 516   // mt row stride in shorts (8B-aligned, bank-staggered)

__device__ __forceinline__ void mfma32(const uint16_t* As, int r0,
                                       const uint16_t* __restrict__ BT2, int cb,
                                       int wn, int l, f32x4 acc[2][2]) {
  #pragma unroll
  for (int kk = 0; kk < 2; kk++) {
    bf16x8 af[2];
    #pragma unroll
    for (int mf = 0; mf < 2; mf++)
      af[mf] = *(const bf16x8*)&As[(r0 + mf * 16 + (l & 15)) * 68 + (l >> 4) * 8 + kk * 32];
    #pragma unroll
    for (int nf = 0; nf < 2; nf++) {
      bf16x8 bv = *(const bf16x8*)&BT2[(size_t)(cb * 128 + wn + nf * 16 + (l & 15)) * 64 +
                                       (l >> 4) * 8 + kk * 32];
      #pragma unroll
      for (int mf = 0; mf < 2; mf++)
        acc[mf][nf] = __builtin_amdgcn_mfma_f32_16x16x32_bf16(af[mf], bv, acc[mf][nf], 0, 0, 0);
    }
  }
}

__device__ __forceinline__ void silu_slot(uint16_t* mt, const float bsv[2], int slot,
                                          int wn, int l, f32x4 acc[2][2]) {
  #pragma unroll
  for (int mf = 0; mf < 2; mf++)
    #pragma unroll
    for (int r = 0; r < 4; r++) {
      int row = mf * 16 + (l >> 4) * 4 + r;
      #pragma unroll
      for (int nf = 0; nf < 2; nf++) {
        int c = wn + nf * 16 + (l & 15);
        mt[row * MTS + c * 4 + slot] = f2bf(siluf(acc[mf][nf][r] + bsv[nf]));
      }
    }
}

__global__ __launch_bounds__(256) void k_edge_all(
    const uint16_t* __restrict__ eap, const int* __restrict__ sndp,
    const int* __restrict__ rcvp, const int* __restrict__ off,
    const float4* __restrict__ edata, const uint16_t* __restrict__ WT2,
    const float* __restrict__ Bd2, const uint16_t* __restrict__ qk_b,
    const uint16_t* __restrict__ qkv_b, const uint16_t* __restrict__ vec_w,
    float* __restrict__ xagg, float* __restrict__ vecagg) {
  __shared__ __align__(16) uint16_t As[64 * 68];     // 8.7 KB
  __shared__ __align__(16) uint16_t mt[32 * MTS];    // 33 KB; slots: 0=xm 1=m1 2=m2 3=dk
  __shared__ float attn_l[32 * 8];                   // 1 KB
  __shared__ int sndl[64], rcvl[64], lo_g[64], hi_g[64];
  __shared__ float4 ed4[64];

  int e0 = blockIdx.x * 64;
  int t = threadIdx.x, l = t & 63, wn = (t >> 6) * 32;

  // ---- meta + A stage + bias regs ----
  if (t < 64) {
    int e = e0 + t;
    int r = rcvp[e];
    sndl[t] = sndp[e]; rcvl[t] = r;
    lo_g[t] = off[r]; hi_g[t] = off[r + 1];
    ed4[t] = edata[e];
  }
  #pragma unroll
  for (int i = 0; i < 2; i++) {
    int c = i * 256 + t;
    int row = c >> 3, ko = (c & 7) * 8;
    *(uint4*)&As[row * 68 + ko] = *(const uint4*)&eap[(size_t)(e0 + row) * 64 + ko];
  }
  float bs[4][2];
  #pragma unroll
  for (int cb = 0; cb < 4; cb++) {
    bs[cb][0] = Bd2[cb * 128 + wn + (l & 15)];
    bs[cb][1] = Bd2[cb * 128 + wn + 16 + (l & 15)];
  }
  __syncthreads();

  #pragma unroll
  for (int half = 0; half < 2; half++) {
    int r0 = half * 32;
    // ---- cb0: dk -> slot 3 ----
    { f32x4 acc[2][2] = {}; mfma32(As, r0, WT2, 0, wn, l, acc); silu_slot(mt, bs[0], 3, wn, l, acc); }
    __syncthreads();
    // ---- phase: q/k loads issued early, cb1-3 MFMA hide them, then attn dot ----
    {
      int el = t >> 3, h = t & 7;
      int ge = r0 + el;
      int rn = rcvl[ge], sn = sndl[ge];
      const uint16_t* qb_ = qk_b + (size_t)rn * 256 + h * 16;
      const uint16_t* kb_ = qk_b + (size_t)sn * 256 + 128 + h * 16;
      uint4 q0 = *(const uint4*)qb_;
      uint4 q1 = *(const uint4*)(qb_ + 8);
      uint4 k0 = *(const uint4*)kb_;
      uint4 k1 = *(const uint4*)(kb_ + 8);
      { f32x4 acc[2][2] = {}; mfma32(As, r0, WT2, 1, wn, l, acc); silu_slot(mt, bs[1], 0, wn, l, acc); }
      { f32x4 acc[2][2] = {}; mfma32(As, r0, WT2, 2, wn, l, acc); silu_slot(mt, bs[2], 1, wn, l, acc); }
      { f32x4 acc[2][2] = {}; mfma32(As, r0, WT2, 3, wn, l, acc); silu_slot(mt, bs[3], 2, wn, l, acc); }
      const uint16_t* dkr = &mt[el * MTS + h * 64 + 3];
      uint32_t qa[8] = {q0.x, q0.y, q0.z, q0.w, q1.x, q1.y, q1.z, q1.w};
      uint32_t ka[8] = {k0.x, k0.y, k0.z, k0.w, k1.x, k1.y, k1.z, k1.w};
      float dot = 0.f;
      #pragma unroll
      for (int j = 0; j < 8; j++) {
        dot += bf2f(qa[j] & 0xffffu) * bf2f(ka[j] & 0xffffu) * bf2f(dkr[j * 8]);
        dot += bf2f(qa[j] >> 16)     * bf2f(ka[j] >> 16)     * bf2f(dkr[j * 8 + 4]);
      }
      attn_l[el * 8 + h] = siluf(dot) * ed4[ge].w;
    }
    __syncthreads();
    // ---- merged walk: thread = (col, 16-edge sub-window); 2 wide gathers/iter ----
    {
      int col = t & 127, sub = t >> 7;
      int i0 = r0 + sub * 16, i1 = i0 + 16;
      int ha = col >> 4;
      float accx = 0.f, a0 = 0.f, a1 = 0.f, a2 = 0.f;
      #pragma unroll 8
      for (int i = i0; i < i1; i++) {
        int li = i - r0;
        int n = rcvl[i], s = sndl[i];
        uint2 vt = *(const uint2*)&qkv_b[(size_t)s * 768 + 256 + col * 4];
        uint2 wt = *(const uint2*)&vec_w[(size_t)s * 512 + col * 4];
        uint2 mr = *(const uint2*)&mt[li * MTS + col * 4];
        float a = attn_l[li * 8 + ha];
        float xmv = bf2f(mr.x & 0xffffu), m1v = bf2f(mr.x >> 16), m2v = bf2f(mr.y & 0xffffu);
        accx += bf2f(vt.x & 0xffffu) * xmv * a;
        float mm1 = bf2f(vt.x >> 16) * m1v;
        float mm2 = bf2f(vt.y & 0xffffu) * m2v;
        float4 ev = ed4[i];
        a0 += bf2f(wt.x & 0xffffu) * mm1 + ev.x * mm2;
        a1 += bf2f(wt.x >> 16)     * mm1 + ev.y * mm2;
        a2 += bf2f(wt.y & 0xffffu) * mm1 + ev.z * mm2;
        if (i == i1 - 1 || rcvl[i + 1] != n) {
          bool cont = (lo_g[i] >= e0 + i0) && (hi_g[i] <= e0 + i1);
          float* dx_ = &xagg[(size_t)n * 128 + col];
          float* d0 = &vecagg[((size_t)n * 3 + 0) * 128 + col];
          float* d1 = &vecagg[((size_t)n * 3 + 1) * 128 + col];
          float* d2 = &vecagg[((size_t)n * 3 + 2) * 128 + col];
          if (cont) { *dx_ = accx; *d0 = a0; *d1 = a1; *d2 = a2; }
          else { atomicAdd(dx_, accx); atomicAdd(d0, a0); atomicAdd(d1, a1); atomicAdd(d2, a2); }
          accx = a0 = a1 = a2 = 0.f;
        }
      }
    }
    __syncthreads();
  }
}

// ---------------- final ----------------
__global__ void k_final(const float* __restrict__ o, const uint16_t* __restrict__ vp,
                        float* __restrict__ dx, float* __restrict__ dvec) {
  int idx = blockIdx.x * 256 + threadIdx.x;
  if (idx >= NN * 128) return;
  int n = idx >> 7, j = idx & 127;
  const float* op = o + (size_t)n * 384;
  float o1 = op[j], o2 = op[128 + j], o3 = op[256 + j];
  const uint16_t* vpn = vp + (size_t)n * 3 * 384;
  float vd = 0.f;
  #pragma unroll
  for (int c = 0; c < 3; c++)
    vd += bf2f(vpn[c * 384 + j]) * bf2f(vpn[c * 384 + 128 + j]);
  dx[idx] = vd * o2 + o3;
  #pragma unroll
  for (int c = 0; c < 3; c++) {
    size_t vi = ((size_t)n * 3 + c) * 128 + j;
    dvec[vi] = bf2f(vpn[c * 384 + 256 + j]) * o1 + dvec[vi];
  }
}

static inline int cdiv_i(long long a, long long b) { return (int)((a + b - 1) / b); }

extern "C" void kernel_launch(void* const* d_in, const int* in_sizes, int n_in,
                              void* d_out, int out_size, void* d_ws, size_t ws_size,
                              hipStream_t stream) {
  const float* x    = (const float*)d_in[0];
  const float* vec  = (const float*)d_in[1];
  const float* ew   = (const float*)d_in[2];
  const float* ea   = (const float*)d_in[3];
  const float* evec = (const float*)d_in[4];
  const int*   snd  = (const int*)d_in[5];
  const int*   rcv  = (const int*)d_in[6];
  const float* ln_s = (const float*)d_in[7];
  const float* ln_b = (const float*)d_in[8];
  const float* Wq = (const float*)d_in[9];   const float* bq = (const float*)d_in[10];
  const float* Wk = (const float*)d_in[11];  const float* bk = (const float*)d_in[12];
  const float* Wv = (const float*)d_in[13];  const float* bv = (const float*)d_in[14];
  const float* Wvec = (const float*)d_in[15];
  const float* Wdk = (const float*)d_in[16]; const float* bdk = (const float*)d_in[17];
  const float* Wdv = (const float*)d_in[18]; const float* bdv = (const float*)d_in[19];
  const float* Wo = (const float*)d_in[20];  const float* bo = (const float*)d_in[21];
  const float* qln_s = (const float*)d_in[22]; const float* qln_b = (const float*)d_in[23];
  const float* kln_s = (const float*)d_in[24]; const float* kln_b = (const float*)d_in[25];
  (void)in_sizes; (void)n_in; (void)ws_size;

  uint8_t* p = (uint8_t*)d_ws;
  auto alloc = [&](size_t bytes) -> uint8_t* {
    uint8_t* r = p; p += (bytes + 255) & ~(size_t)255; return r;
  };
  uint16_t* WTqkv = (uint16_t*)alloc(768 * 128 * 2);
  float*    Bqkv  = (float*)alloc(768 * 4);
  uint16_t* WTvec = (uint16_t*)alloc(384 * 128 * 2);
  uint16_t* WTdkv = (uint16_t*)alloc(512 * 64 * 2);
  float*    Bdkv  = (float*)alloc(512 * 4);
  uint16_t* WTo   = (uint16_t*)alloc(384 * 128 * 2);
  int*      deg   = (int*)alloc(NN * 4);
  int*      off   = (int*)alloc((NN + 1) * 4);
  int*      cur   = (int*)alloc(NN * 4);
  int*      bsum  = (int*)alloc(256 * 4);
  int*      perm  = (int*)alloc((size_t)NE * 4);
  int*      sndp  = (int*)alloc((size_t)NE * 4);
  int*      rcvp  = (int*)alloc((size_t)NE * 4);
  float4*   edata = (float4*)alloc((size_t)NE * 16);
  uint16_t* ea_perm = (uint16_t*)alloc((size_t)NE * 64 * 2);
  uint16_t* xn_b  = (uint16_t*)alloc((size_t)NN * 128 * 2);
  uint16_t* qkv_b = (uint16_t*)alloc((size_t)NN * 768 * 2);
  uint16_t* qk_b  = (uint16_t*)alloc((size_t)NN * 256 * 2);
  uint16_t* vec_b = (uint16_t*)alloc((size_t)NN * 3 * 128 * 2);
  uint16_t* vec_w = (uint16_t*)alloc((size_t)NN * 512 * 2);
  uint16_t* vp    = (uint16_t*)alloc((size_t)NN * 3 * 384 * 2);
  float*    o      = (float*)alloc((size_t)NN * 384 * 4);
  uint16_t* xagg_b = (uint16_t*)alloc((size_t)NN * 128 * 2);

  float* xagg   = (float*)d_out;
  float* vecagg = (float*)d_out + (size_t)NN * 128;

  hipMemsetAsync(d_out, 0, (size_t)out_size * 4, stream);

  // ---- weights prep (1 launch) ----
  k_prep<<<cdiv_i(98304 + 49152 + 32768 + 49152 + 1280, 256), 256, 0, stream>>>(
      Wq, Wk, Wv, Wvec, Wdk, Wdv, Wo, bq, bk, bv, bdk, bdv,
      WTqkv, WTvec, WTdkv, WTo, Bqkv, Bdkv);

  // ---- edge sort by receiver ----
  int NSB = cdiv_i(NN, 256);
  hipMemsetAsync(deg, 0, NN * 4, stream);
  k_hist<<<cdiv_i(NE, 256), 256, 0, stream>>>(rcv, deg);
  k_scan1<<<NSB, 256, 0, stream>>>(deg, bsum);
  k_scan2<<<1, 64, 0, stream>>>(bsum, NSB, off);
  k_scan3<<<NSB, 256, 0, stream>>>(deg, bsum, off, cur);
  k_scatter<<<cdiv_i(NE, 256), 256, 0, stream>>>(rcv, cur, perm);
  k_permute<<<cdiv_i((long long)NE * 16, 256), 256, 0, stream>>>(ea, perm, snd, rcv, ew, evec,
                                                                 ea_perm, sndp, rcvp, edata);

  // ---- node pre (1 launch: LN + vec GEMM-layout + vec walk-layout) ----
  k_node_pre<<<30000, 256, 0, stream>>>(x, ln_s, ln_b, vec, xn_b, vec_b, vec_w);

  // qkv = xn @ [Wq|Wk|Wv-interleaved] + b  (bf16 out, Fo=768)
  { dim3 g(768 / 128, cdiv_i(NN, 128));
    k_gemm<128, true, false><<<g, 256, 0, stream>>>(xn_b, WTqkv, Bqkv, qkv_b, NN, 768); }
  k_headln<<<cdiv_i((long long)NN * 16, 256), 256, 0, stream>>>(qkv_b, qln_s, qln_b, kln_s, kln_b, qk_b);

  // vp = vec @ Wvec (bf16 out)
  { dim3 g(384 / 128, cdiv_i((long long)NN * 3, 128));
    k_gemm<128, true, false><<<g, 256, 0, stream>>>(vec_b, WTvec, nullptr, vp, NN * 3, 384); }

  // ---- fully fused edge phase ----
  k_edge_all<<<NE / 64, 256, 0, stream>>>(ea_perm, sndp, rcvp, off, edata, WTdkv, Bdkv,
                                          qk_b, qkv_b, vec_w, xagg, vecagg);

  // o = x_agg @ Wo + bo
  k_cast_bf16<<<cdiv_i((long long)NN * 64, 256), 256, 0, stream>>>(xagg, xagg_b, NN * 64);
  { dim3 g(384 / 128, cdiv_i(NN, 128));
    k_gemm<128, false, false><<<g, 256, 0, stream>>>(xagg_b, WTo, bo, o, NN, 384); }

  // outputs
  k_final<<<cdiv_i((long long)NN * 128, 256), 256, 0, stream>>>(o, vp, xagg, vecagg);
}